// Round 1
// baseline (16911.945 us; speedup 1.0000x reference)
//
#include <hip/hip_runtime.h>
#include <math.h>

// Problem dims
#define B_ 4096
#define HOR_ 32
#define L_ 512
#define A_ 64
#define HID_ 1024

// GEMM tile config
#define BM 128
#define BN 64
#define BK 16

// C[M,N] = act(A @ W + bias [+ R]) ; A row-major with row stride lda,
// W [K,N] row-major, C row stride ldc, R row stride ldr (residual, may be null).
__global__ __launch_bounds__(256) void gemm_kernel(
    const float* __restrict__ A, int lda,
    const float* __restrict__ W, int N,
    const float* __restrict__ bias,
    const float* __restrict__ R, int ldr,
    float* __restrict__ C, int ldc,
    int K, int do_relu)
{
    __shared__ float As[BK][BM];
    __shared__ float Bs[BK][BN];
    const int tid = threadIdx.x;
    const int tx = tid & 15;   // -> N (4 cols)
    const int ty = tid >> 4;   // -> M (8 rows)
    const int m0 = blockIdx.y * BM;
    const int n0 = blockIdx.x * BN;

    float acc[8][4];
#pragma unroll
    for (int i = 0; i < 8; ++i)
#pragma unroll
        for (int j = 0; j < 4; ++j) acc[i][j] = 0.f;

    for (int k0 = 0; k0 < K; k0 += BK) {
        // stage A tile: 128 rows x 16 k = 512 float4, 2 per thread
#pragma unroll
        for (int s = 0; s < 2; ++s) {
            int f4 = tid + s * 256;
            int row = f4 >> 2;
            int kq = f4 & 3;
            float4 v = *reinterpret_cast<const float4*>(
                &A[(long)(m0 + row) * lda + k0 + kq * 4]);
            As[kq * 4 + 0][row] = v.x;
            As[kq * 4 + 1][row] = v.y;
            As[kq * 4 + 2][row] = v.z;
            As[kq * 4 + 3][row] = v.w;
        }
        // stage B tile: 16 k x 64 n = 256 float4, 1 per thread
        {
            int kr = tid >> 4;
            int nc = tid & 15;
            float4 v = *reinterpret_cast<const float4*>(
                &W[(long)(k0 + kr) * N + n0 + nc * 4]);
            *reinterpret_cast<float4*>(&Bs[kr][nc * 4]) = v;
        }
        __syncthreads();
#pragma unroll
        for (int k = 0; k < BK; ++k) {
            float a[8], b[4];
            *(float4*)&a[0] = *(float4*)&As[k][ty * 8];
            *(float4*)&a[4] = *(float4*)&As[k][ty * 8 + 4];
            *(float4*)&b[0] = *(float4*)&Bs[k][tx * 4];
#pragma unroll
            for (int i = 0; i < 8; ++i)
#pragma unroll
                for (int j = 0; j < 4; ++j)
                    acc[i][j] = fmaf(a[i], b[j], acc[i][j]);
        }
        __syncthreads();
    }

    // epilogue
    float4 bb = *reinterpret_cast<const float4*>(&bias[n0 + tx * 4]);
#pragma unroll
    for (int i = 0; i < 8; ++i) {
        int row = m0 + ty * 8 + i;
        float4 v;
        v.x = acc[i][0] + bb.x;
        v.y = acc[i][1] + bb.y;
        v.z = acc[i][2] + bb.z;
        v.w = acc[i][3] + bb.w;
        if (R) {
            float4 r = *reinterpret_cast<const float4*>(
                &R[(long)row * ldr + n0 + tx * 4]);
            v.x += r.x; v.y += r.y; v.z += r.z; v.w += r.w;
        }
        if (do_relu) {
            v.x = fmaxf(v.x, 0.f);
            v.y = fmaxf(v.y, 0.f);
            v.z = fmaxf(v.z, 0.f);
            v.w = fmaxf(v.w, 0.f);
        }
        *reinterpret_cast<float4*>(&C[(long)row * ldc + n0 + tx * 4]) = v;
    }
}

// Build sae = [state, action@Wae+bae] and sa = [state, action] for step t.
__global__ __launch_bounds__(576) void prep_kernel(
    const float* __restrict__ states,   // d_out states base [B][33][512]
    int t,
    const float* __restrict__ actions,  // [B][32][64]
    const float* __restrict__ Wae,      // [64][64]
    const float* __restrict__ bae,      // [64]
    float* __restrict__ sae,            // [B][576]
    float* __restrict__ sa)             // [B][576]
{
    const int b = blockIdx.x;
    const int tid = threadIdx.x;
    const float* srow = states + (long)b * (33 * L_) + (long)t * L_;
    const float* arow = actions + (long)b * (HOR_ * A_) + (long)t * A_;
    if (tid < L_) {
        float s = srow[tid];
        sae[(long)b * 576 + tid] = s;
        sa[(long)b * 576 + tid] = s;
    } else {
        int c = tid - L_;
        float acc = bae[c];
#pragma unroll 8
        for (int k = 0; k < A_; ++k)
            acc = fmaf(arow[k], Wae[k * A_ + c], acc);
        sae[(long)b * 576 + L_ + c] = acc;
        sa[(long)b * 576 + L_ + c] = arow[c];
    }
}

// harm[:, t] = sigmoid(hh @ Wh2 + bh2), one wave per row.
__global__ __launch_bounds__(256) void harm_kernel(
    const float* __restrict__ hh,   // [B][1024]
    const float* __restrict__ Wh2,  // [1024]
    const float* __restrict__ bh2,  // [1]
    float* __restrict__ harm,       // [B][32]
    int t)
{
    const int wave = threadIdx.x >> 6;
    const int lane = threadIdx.x & 63;
    const int r = blockIdx.x * 4 + wave;
    const float* row = hh + (long)r * HID_;
    float s = 0.f;
#pragma unroll
    for (int q = 0; q < 4; ++q) {
        int idx = (q * 64 + lane) * 4;
        float4 h4 = *reinterpret_cast<const float4*>(&row[idx]);
        float4 w4 = *reinterpret_cast<const float4*>(&Wh2[idx]);
        s += h4.x * w4.x + h4.y * w4.y + h4.z * w4.z + h4.w * w4.w;
    }
#pragma unroll
    for (int off = 32; off; off >>= 1) s += __shfl_down(s, off);
    if (lane == 0) {
        float x = s + bh2[0];
        harm[(long)r * HOR_ + t] = 1.f / (1.f + expf(-x));
    }
}

// states[:, 0, :] = initial_state
__global__ __launch_bounds__(256) void init_states_kernel(
    const float* __restrict__ init, float* __restrict__ states)
{
    long i = (long)blockIdx.x * 256 + threadIdx.x;  // over B*L
    long b = i >> 9;
    long l = i & 511;
    states[b * (33 * L_) + l] = init[i];
}

extern "C" void kernel_launch(void* const* d_in, const int* in_sizes, int n_in,
                              void* d_out, int out_size, void* d_ws, size_t ws_size,
                              hipStream_t stream)
{
    const float* initial = (const float*)d_in[0];
    const float* actions = (const float*)d_in[1];
    const float* Wae = (const float*)d_in[2];
    const float* bae = (const float*)d_in[3];
    const float* Wt1 = (const float*)d_in[4];
    const float* bt1 = (const float*)d_in[5];
    const float* Wt2 = (const float*)d_in[6];
    const float* bt2 = (const float*)d_in[7];
    const float* Wt3 = (const float*)d_in[8];
    const float* bt3 = (const float*)d_in[9];
    const float* Wo1 = (const float*)d_in[10];
    const float* bo1 = (const float*)d_in[11];
    const float* Wo2 = (const float*)d_in[12];
    const float* bo2 = (const float*)d_in[13];
    const float* Wh1 = (const float*)d_in[14];
    const float* bh1 = (const float*)d_in[15];
    const float* Wh2 = (const float*)d_in[16];
    const float* bh2 = (const float*)d_in[17];

    float* out = (float*)d_out;
    float* states = out;                                    // [B][33][512]
    float* obs = out + (size_t)B_ * 33 * L_;                // [B][32][512]
    float* harm = obs + (size_t)B_ * HOR_ * L_;             // [B][32]

    float* sae = (float*)d_ws;                              // [B][576]
    float* sa = sae + (size_t)B_ * 576;                     // [B][576]
    float* buf0 = sa + (size_t)B_ * 576;                    // [B][1024]
    float* buf1 = buf0 + (size_t)B_ * HID_;                 // [B][1024]

    // states[:,0,:] = initial
    init_states_kernel<<<(B_ * L_) / 256, 256, 0, stream>>>(initial, states);

    const int ldS = 33 * L_;  // states row stride

    for (int t = 0; t < HOR_; ++t) {
        const float* st = states + (long)t * L_;  // row stride ldS

        // build sae = [state, ae], sa = [state, action]
        prep_kernel<<<B_, 576, 0, stream>>>(states, t, actions, Wae, bae, sae, sa);

        // harm path: hh = relu(sa @ Wh1 + bh1); harm = sigmoid(hh @ Wh2 + bh2)
        gemm_kernel<<<dim3(HID_ / BN, B_ / BM), 256, 0, stream>>>(
            sa, 576, Wh1, HID_, bh1, nullptr, 0, buf0, HID_, 576, 1);
        harm_kernel<<<B_ / 4, 256, 0, stream>>>(buf0, Wh2, bh2, harm, t);

        // obs path: oh = relu(state @ Wo1 + bo1); obs[:,t] = oh @ Wo2 + bo2
        gemm_kernel<<<dim3(HID_ / BN, B_ / BM), 256, 0, stream>>>(
            st, ldS, Wo1, HID_, bo1, nullptr, 0, buf0, HID_, L_, 1);
        gemm_kernel<<<dim3(L_ / BN, B_ / BM), 256, 0, stream>>>(
            buf0, HID_, Wo2, L_, bo2, nullptr, 0, obs + (long)t * L_, HOR_ * L_,
            HID_, 0);

        // transition: h1 = relu(sae@Wt1+bt1); h2 = relu(h1@Wt2+bt2);
        // next = state + h2@Wt3 + bt3
        gemm_kernel<<<dim3(HID_ / BN, B_ / BM), 256, 0, stream>>>(
            sae, 576, Wt1, HID_, bt1, nullptr, 0, buf0, HID_, 576, 1);
        gemm_kernel<<<dim3(HID_ / BN, B_ / BM), 256, 0, stream>>>(
            buf0, HID_, Wt2, HID_, bt2, nullptr, 0, buf1, HID_, HID_, 1);
        gemm_kernel<<<dim3(L_ / BN, B_ / BM), 256, 0, stream>>>(
            buf1, HID_, Wt3, L_, bt3, st, ldS, states + (long)(t + 1) * L_, ldS,
            HID_, 0);
    }
}

// Round 2
// 10839.612 us; speedup vs baseline: 1.5602x; 1.5602x over previous
//
#include <hip/hip_runtime.h>
#include <math.h>

// Problem dims
#define B_ 4096
#define HOR_ 32
#define L_ 512
#define A_ 64
#define HID_ 1024

// f32 GEMM tile config (phase 1, transition path — precision-critical)
#define BM 128
#define BN 64
#define BK 16

// phase-2 chunking
#define CB 512            // batch rows per chunk
#define MC (CB * HOR_)    // 16384 rows per chunk

typedef unsigned short ushort_t;
typedef __attribute__((ext_vector_type(4))) float f32x4;
typedef __attribute__((ext_vector_type(8))) short s16x8;
typedef __attribute__((ext_vector_type(4))) short s16x4;

__device__ __forceinline__ unsigned short bf16_rne(float x) {
    unsigned u = __builtin_bit_cast(unsigned, x);
    u += 0x7fffu + ((u >> 16) & 1u);
    return (unsigned short)(u >> 16);
}
__device__ __forceinline__ float bf16_to_f32(unsigned short h) {
    unsigned u = ((unsigned)h) << 16;
    return __builtin_bit_cast(float, u);
}

// ---------------- Phase 1: exact-f32 GEMM (transition chain) ----------------
// C[M,N] = act(A @ W + bias [+ R])
__global__ __launch_bounds__(256) void gemm_kernel(
    const float* __restrict__ A, int lda,
    const float* __restrict__ W, int N,
    const float* __restrict__ bias,
    const float* __restrict__ R, int ldr,
    float* __restrict__ C, int ldc,
    int K, int do_relu)
{
    __shared__ float As[BK][BM];
    __shared__ float Bs[BK][BN];
    const int tid = threadIdx.x;
    const int tx = tid & 15;   // -> N (4 cols)
    const int ty = tid >> 4;   // -> M (8 rows)
    const int m0 = blockIdx.y * BM;
    const int n0 = blockIdx.x * BN;

    float acc[8][4];
#pragma unroll
    for (int i = 0; i < 8; ++i)
#pragma unroll
        for (int j = 0; j < 4; ++j) acc[i][j] = 0.f;

    for (int k0 = 0; k0 < K; k0 += BK) {
#pragma unroll
        for (int s = 0; s < 2; ++s) {
            int f4 = tid + s * 256;
            int row = f4 >> 2;
            int kq = f4 & 3;
            float4 v = *reinterpret_cast<const float4*>(
                &A[(long)(m0 + row) * lda + k0 + kq * 4]);
            As[kq * 4 + 0][row] = v.x;
            As[kq * 4 + 1][row] = v.y;
            As[kq * 4 + 2][row] = v.z;
            As[kq * 4 + 3][row] = v.w;
        }
        {
            int kr = tid >> 4;
            int nc = tid & 15;
            float4 v = *reinterpret_cast<const float4*>(
                &W[(long)(k0 + kr) * N + n0 + nc * 4]);
            *reinterpret_cast<float4*>(&Bs[kr][nc * 4]) = v;
        }
        __syncthreads();
#pragma unroll
        for (int k = 0; k < BK; ++k) {
            float a[8], b[4];
            *(float4*)&a[0] = *(float4*)&As[k][ty * 8];
            *(float4*)&a[4] = *(float4*)&As[k][ty * 8 + 4];
            *(float4*)&b[0] = *(float4*)&Bs[k][tx * 4];
#pragma unroll
            for (int i = 0; i < 8; ++i)
#pragma unroll
                for (int j = 0; j < 4; ++j)
                    acc[i][j] = fmaf(a[i], b[j], acc[i][j]);
        }
        __syncthreads();
    }

    float4 bb = *reinterpret_cast<const float4*>(&bias[n0 + tx * 4]);
#pragma unroll
    for (int i = 0; i < 8; ++i) {
        int row = m0 + ty * 8 + i;
        float4 v;
        v.x = acc[i][0] + bb.x;
        v.y = acc[i][1] + bb.y;
        v.z = acc[i][2] + bb.z;
        v.w = acc[i][3] + bb.w;
        if (R) {
            float4 r = *reinterpret_cast<const float4*>(
                &R[(long)row * ldr + n0 + tx * 4]);
            v.x += r.x; v.y += r.y; v.z += r.z; v.w += r.w;
        }
        if (do_relu) {
            v.x = fmaxf(v.x, 0.f);
            v.y = fmaxf(v.y, 0.f);
            v.z = fmaxf(v.z, 0.f);
            v.w = fmaxf(v.w, 0.f);
        }
        *reinterpret_cast<float4*>(&C[(long)row * ldc + n0 + tx * 4]) = v;
    }
}

// Build sae = [state, action@Wae+bae] for step t (f32, exact).
__global__ __launch_bounds__(576) void prep_kernel(
    const float* __restrict__ states,   // [B][33][512]
    int t,
    const float* __restrict__ actions,  // [B][32][64]
    const float* __restrict__ Wae,      // [64][64]
    const float* __restrict__ bae,      // [64]
    float* __restrict__ sae)            // [B][576]
{
    const int b = blockIdx.x;
    const int tid = threadIdx.x;
    const float* srow = states + (long)b * (33 * L_) + (long)t * L_;
    const float* arow = actions + (long)b * (HOR_ * A_) + (long)t * A_;
    if (tid < L_) {
        sae[(long)b * 576 + tid] = srow[tid];
    } else {
        int c = tid - L_;
        float acc = bae[c];
#pragma unroll 8
        for (int k = 0; k < A_; ++k)
            acc = fmaf(arow[k], Wae[k * A_ + c], acc);
        sae[(long)b * 576 + L_ + c] = acc;
    }
}

// states[:, 0, :] = initial_state
__global__ __launch_bounds__(256) void init_states_kernel(
    const float* __restrict__ init, float* __restrict__ states)
{
    long i = (long)blockIdx.x * 256 + threadIdx.x;
    long b = i >> 9;
    long l = i & 511;
    states[b * (33 * L_) + l] = init[i];
}

// ---------------- Phase 2: batched bf16 MFMA (obs + harm paths) -------------

// WT[n][k] = bf16(W[k][n])   (cast + transpose, once per call)
__global__ __launch_bounds__(256) void cast_transpose(
    const float* __restrict__ W, ushort_t* __restrict__ WT, int K, int N)
{
    int k = blockIdx.x * 256 + threadIdx.x;
    int n = blockIdx.y;
    if (k < K) WT[(long)n * K + k] = bf16_rne(W[(long)k * N + n]);
}

// Out[m][n] (bf16) = relu( A[m][:] @ WT^T + bias ), A f32 with hi/lo split.
// A rows: m -> states row (m>>5)*33 + (m&31)  (cols 0..511), actions row m
// (cols 512..Ktot-1).
__global__ __launch_bounds__(256) void mm_split(
    const float* __restrict__ Astate,  // chunk base of states [..][33][512]
    const float* __restrict__ Aact,    // chunk base of actions [CB*32][64]
    int Ktot,                          // 512 or 576 (multiple of 32)
    const ushort_t* __restrict__ WT,   // [N][Ktot] bf16
    int N,
    const float* __restrict__ bias,
    ushort_t* __restrict__ Out)        // [MC][N] bf16
{
    __shared__ ushort_t Ahi[128][40];  // padded: stride 40 halves = 80 B
    __shared__ ushort_t Alo[128][40];
    __shared__ ushort_t Bt[128][40];   // WT tile: [n][k]

    const int tid = threadIdx.x;
    const int m0 = blockIdx.y * 128;
    const int n0 = blockIdx.x * 128;
    const int w = tid >> 6;
    const int l = tid & 63;
    const int wm = w >> 1, wn = w & 1;
    const int kg = l >> 4, lr = l & 15;

    f32x4 acc[4][4] = {};

    for (int k0 = 0; k0 < Ktot; k0 += 32) {
        // stage A (f32 -> bf16 hi/lo): 128 rows x 32 cols
#pragma unroll
        for (int s = 0; s < 4; ++s) {
            int idx = tid + s * 256;
            int arow = idx >> 3;
            int ch = idx & 7;      // 16B chunk (4 floats)
            int m = m0 + arow;
            const float* src;
            if (k0 < L_) {
                src = Astate + (long)((m >> 5) * 33 + (m & 31)) * L_ + k0 + ch * 4;
            } else {
                src = Aact + (long)m * A_ + (k0 - L_) + ch * 4;
            }
            float4 v = *reinterpret_cast<const float4*>(src);
            unsigned short h0 = bf16_rne(v.x), h1 = bf16_rne(v.y),
                           h2 = bf16_rne(v.z), h3 = bf16_rne(v.w);
            unsigned short e0 = bf16_rne(v.x - bf16_to_f32(h0));
            unsigned short e1 = bf16_rne(v.y - bf16_to_f32(h1));
            unsigned short e2 = bf16_rne(v.z - bf16_to_f32(h2));
            unsigned short e3 = bf16_rne(v.w - bf16_to_f32(h3));
            s16x4 hv = {(short)h0, (short)h1, (short)h2, (short)h3};
            s16x4 lv = {(short)e0, (short)e1, (short)e2, (short)e3};
            *reinterpret_cast<s16x4*>(&Ahi[arow][ch * 4]) = hv;
            *reinterpret_cast<s16x4*>(&Alo[arow][ch * 4]) = lv;
        }
        // stage B (bf16 WT rows): 128 n-rows x 32 k
#pragma unroll
        for (int s = 0; s < 2; ++s) {
            int idx = tid + s * 256;
            int brow = idx >> 2;
            int ch = idx & 3;      // 16B chunk (8 halves)
            s16x8 wv = *reinterpret_cast<const s16x8*>(
                &WT[(long)(n0 + brow) * Ktot + k0 + ch * 8]);
            *reinterpret_cast<s16x8*>(&Bt[brow][ch * 8]) = wv;
        }
        __syncthreads();

        s16x8 ah[4], al[4], bb[4];
#pragma unroll
        for (int i = 0; i < 4; ++i) {
            int r = wm * 64 + i * 16 + lr;
            ah[i] = *reinterpret_cast<const s16x8*>(&Ahi[r][kg * 8]);
            al[i] = *reinterpret_cast<const s16x8*>(&Alo[r][kg * 8]);
        }
#pragma unroll
        for (int j = 0; j < 4; ++j) {
            int r = wn * 64 + j * 16 + lr;
            bb[j] = *reinterpret_cast<const s16x8*>(&Bt[r][kg * 8]);
        }
#pragma unroll
        for (int i = 0; i < 4; ++i)
#pragma unroll
            for (int j = 0; j < 4; ++j) {
                acc[i][j] = __builtin_amdgcn_mfma_f32_16x16x32_bf16(
                    ah[i], bb[j], acc[i][j], 0, 0, 0);
                acc[i][j] = __builtin_amdgcn_mfma_f32_16x16x32_bf16(
                    al[i], bb[j], acc[i][j], 0, 0, 0);
            }
        __syncthreads();
    }

    float bv[4];
#pragma unroll
    for (int j = 0; j < 4; ++j) bv[j] = bias[n0 + wn * 64 + j * 16 + lr];
#pragma unroll
    for (int i = 0; i < 4; ++i)
#pragma unroll
        for (int j = 0; j < 4; ++j)
#pragma unroll
            for (int r = 0; r < 4; ++r) {
                int row = m0 + wm * 64 + i * 16 + kg * 4 + r;
                int col = n0 + wn * 64 + j * 16 + lr;
                float v = fmaxf(acc[i][j][r] + bv[j], 0.f);
                Out[(long)row * N + col] = bf16_rne(v);
            }
}

// Out[m][n] (f32) = A_bf16[m][:] @ WT^T + bias   (K = 1024, no relu)
__global__ __launch_bounds__(256) void mm_bf16(
    const ushort_t* __restrict__ Abf,  // [MC][1024] bf16
    const ushort_t* __restrict__ WT,   // [N][1024] bf16
    int N,
    const float* __restrict__ bias,
    float* __restrict__ Out)           // [MC][N] f32
{
    __shared__ ushort_t At[128][40];
    __shared__ ushort_t Bt[128][40];

    const int tid = threadIdx.x;
    const int m0 = blockIdx.y * 128;
    const int n0 = blockIdx.x * 128;
    const int w = tid >> 6;
    const int l = tid & 63;
    const int wm = w >> 1, wn = w & 1;
    const int kg = l >> 4, lr = l & 15;

    f32x4 acc[4][4] = {};

    for (int k0 = 0; k0 < HID_; k0 += 32) {
#pragma unroll
        for (int s = 0; s < 2; ++s) {
            int idx = tid + s * 256;
            int arow = idx >> 2;
            int ch = idx & 3;
            s16x8 av = *reinterpret_cast<const s16x8*>(
                &Abf[(long)(m0 + arow) * HID_ + k0 + ch * 8]);
            *reinterpret_cast<s16x8*>(&At[arow][ch * 8]) = av;
        }
#pragma unroll
        for (int s = 0; s < 2; ++s) {
            int idx = tid + s * 256;
            int brow = idx >> 2;
            int ch = idx & 3;
            s16x8 wv = *reinterpret_cast<const s16x8*>(
                &WT[(long)(n0 + brow) * HID_ + k0 + ch * 8]);
            *reinterpret_cast<s16x8*>(&Bt[brow][ch * 8]) = wv;
        }
        __syncthreads();

        s16x8 aa[4], bb[4];
#pragma unroll
        for (int i = 0; i < 4; ++i)
            aa[i] = *reinterpret_cast<const s16x8*>(&At[wm * 64 + i * 16 + lr][kg * 8]);
#pragma unroll
        for (int j = 0; j < 4; ++j)
            bb[j] = *reinterpret_cast<const s16x8*>(&Bt[wn * 64 + j * 16 + lr][kg * 8]);
#pragma unroll
        for (int i = 0; i < 4; ++i)
#pragma unroll
            for (int j = 0; j < 4; ++j)
                acc[i][j] = __builtin_amdgcn_mfma_f32_16x16x32_bf16(
                    aa[i], bb[j], acc[i][j], 0, 0, 0);
        __syncthreads();
    }

    float bv[4];
#pragma unroll
    for (int j = 0; j < 4; ++j) bv[j] = bias[n0 + wn * 64 + j * 16 + lr];
#pragma unroll
    for (int i = 0; i < 4; ++i)
#pragma unroll
        for (int j = 0; j < 4; ++j)
#pragma unroll
            for (int r = 0; r < 4; ++r) {
                int row = m0 + wm * 64 + i * 16 + kg * 4 + r;
                int col = n0 + wn * 64 + j * 16 + lr;
                Out[(long)row * N + col] = acc[i][j][r] + bv[j];
            }
}

// harm[m] = sigmoid(hh[m][:] . Wh2 + bh2), one wave per row.
__global__ __launch_bounds__(256) void harm_reduce(
    const ushort_t* __restrict__ hh,  // [MC][1024] bf16
    const float* __restrict__ Wh2,    // [1024]
    const float* __restrict__ bh2,
    float* __restrict__ harm)         // chunk base, linear
{
    const int wave = threadIdx.x >> 6;
    const int lane = threadIdx.x & 63;
    const long r = (long)blockIdx.x * 4 + wave;
    const ushort_t* row = hh + r * HID_;
    float s = 0.f;
#pragma unroll
    for (int q = 0; q < 2; ++q) {
        s16x8 a = *reinterpret_cast<const s16x8*>(&row[lane * 16 + q * 8]);
        float4 w0 = *reinterpret_cast<const float4*>(&Wh2[lane * 16 + q * 8]);
        float4 w1 = *reinterpret_cast<const float4*>(&Wh2[lane * 16 + q * 8 + 4]);
        s = fmaf(bf16_to_f32((unsigned short)a[0]), w0.x, s);
        s = fmaf(bf16_to_f32((unsigned short)a[1]), w0.y, s);
        s = fmaf(bf16_to_f32((unsigned short)a[2]), w0.z, s);
        s = fmaf(bf16_to_f32((unsigned short)a[3]), w0.w, s);
        s = fmaf(bf16_to_f32((unsigned short)a[4]), w1.x, s);
        s = fmaf(bf16_to_f32((unsigned short)a[5]), w1.y, s);
        s = fmaf(bf16_to_f32((unsigned short)a[6]), w1.z, s);
        s = fmaf(bf16_to_f32((unsigned short)a[7]), w1.w, s);
    }
#pragma unroll
    for (int off = 32; off; off >>= 1) s += __shfl_down(s, off);
    if (lane == 0) {
        float x = s + bh2[0];
        harm[r] = 1.f / (1.f + expf(-x));
    }
}

// ---------------------------------------------------------------------------
extern "C" void kernel_launch(void* const* d_in, const int* in_sizes, int n_in,
                              void* d_out, int out_size, void* d_ws, size_t ws_size,
                              hipStream_t stream)
{
    const float* initial = (const float*)d_in[0];
    const float* actions = (const float*)d_in[1];
    const float* Wae = (const float*)d_in[2];
    const float* bae = (const float*)d_in[3];
    const float* Wt1 = (const float*)d_in[4];
    const float* bt1 = (const float*)d_in[5];
    const float* Wt2 = (const float*)d_in[6];
    const float* bt2 = (const float*)d_in[7];
    const float* Wt3 = (const float*)d_in[8];
    const float* bt3 = (const float*)d_in[9];
    const float* Wo1 = (const float*)d_in[10];
    const float* bo1 = (const float*)d_in[11];
    const float* Wo2 = (const float*)d_in[12];
    const float* bo2 = (const float*)d_in[13];
    const float* Wh1 = (const float*)d_in[14];
    const float* bh1 = (const float*)d_in[15];
    const float* Wh2 = (const float*)d_in[16];
    const float* bh2 = (const float*)d_in[17];

    float* out = (float*)d_out;
    float* states = out;                                    // [B][33][512]
    float* obs = out + (size_t)B_ * 33 * L_;                // [B][32][512]
    float* harm = obs + (size_t)B_ * HOR_ * L_;             // [B][32]

    // ws layout
    char* wsb = (char*)d_ws;
    ushort_t* WT_o1 = (ushort_t*)wsb;                       // [1024][512]
    ushort_t* WT_o2 = WT_o1 + (size_t)HID_ * L_;            // [512][1024]
    ushort_t* WT_h1 = WT_o2 + (size_t)L_ * HID_;            // [1024][576]
    char* fbase = (char*)(WT_h1 + (size_t)HID_ * 576);
    float* sae = (float*)fbase;                             // [B][576]
    float* buf0 = sae + (size_t)B_ * 576;                   // [B][1024]
    float* buf1 = buf0 + (size_t)B_ * HID_;                 // [B][1024]
    ushort_t* oh = (ushort_t*)fbase;                        // [MC][1024] bf16 (phase 2, reuses phase-1 region)

    // one-time weight prep
    cast_transpose<<<dim3(2, HID_), 256, 0, stream>>>(Wo1, WT_o1, L_, HID_);
    cast_transpose<<<dim3(4, L_), 256, 0, stream>>>(Wo2, WT_o2, HID_, L_);
    cast_transpose<<<dim3(3, HID_), 256, 0, stream>>>(Wh1, WT_h1, 576, HID_);

    init_states_kernel<<<(B_ * L_) / 256, 256, 0, stream>>>(initial, states);

    const int ldS = 33 * L_;

    // ---- Phase 1: serial transition rollout (exact f32) ----
    for (int t = 0; t < HOR_; ++t) {
        const float* st = states + (long)t * L_;
        prep_kernel<<<B_, 576, 0, stream>>>(states, t, actions, Wae, bae, sae);
        gemm_kernel<<<dim3(HID_ / BN, B_ / BM), 256, 0, stream>>>(
            sae, 576, Wt1, HID_, bt1, nullptr, 0, buf0, HID_, 576, 1);
        gemm_kernel<<<dim3(HID_ / BN, B_ / BM), 256, 0, stream>>>(
            buf0, HID_, Wt2, HID_, bt2, nullptr, 0, buf1, HID_, HID_, 1);
        gemm_kernel<<<dim3(L_ / BN, B_ / BM), 256, 0, stream>>>(
            buf1, HID_, Wt3, L_, bt3, st, ldS, states + (long)(t + 1) * L_, ldS,
            HID_, 0);
    }

    // ---- Phase 2: batched obs + harm in bf16 MFMA, 8 chunks of 512 batch ----
    for (int c = 0; c < B_ / CB; ++c) {
        const float* Sc = states + (size_t)c * CB * 33 * L_;
        const float* Ac = actions + (size_t)c * CB * HOR_ * A_;
        // obs1: oh = relu(state @ Wo1 + bo1)    [MC x 1024], K=512
        mm_split<<<dim3(HID_ / 128, MC / 128), 256, 0, stream>>>(
            Sc, nullptr, L_, WT_o1, HID_, bo1, oh);
        // obs2: obs = oh @ Wo2 + bo2            [MC x 512]
        mm_bf16<<<dim3(L_ / 128, MC / 128), 256, 0, stream>>>(
            oh, WT_o2, L_, bo2, obs + (size_t)c * CB * HOR_ * L_);
        // harm1: hh = relu([state, action] @ Wh1 + bh1)  [MC x 1024], K=576
        mm_split<<<dim3(HID_ / 128, MC / 128), 256, 0, stream>>>(
            Sc, Ac, 576, WT_h1, HID_, bh1, oh);
        // harm2
        harm_reduce<<<MC / 4, 256, 0, stream>>>(
            oh, Wh2, bh2, harm + (size_t)c * CB * HOR_);
    }
}

// Round 3
// 5708.644 us; speedup vs baseline: 2.9625x; 1.8988x over previous
//
#include <hip/hip_runtime.h>
#include <math.h>

// Problem dims
#define B_ 4096
#define HOR_ 32
#define L_ 512
#define A_ 64
#define HID_ 1024

// phase-2 chunking
#define CB 512            // batch rows per chunk
#define MC (CB * HOR_)    // 16384 rows per chunk

typedef unsigned short ushort_t;
typedef __attribute__((ext_vector_type(4))) float f32x4;
typedef __attribute__((ext_vector_type(8))) short s16x8;
typedef __attribute__((ext_vector_type(4))) short s16x4;
typedef __attribute__((ext_vector_type(8))) _Float16 f16x8;

__device__ __forceinline__ unsigned short bf16_rne(float x) {
    unsigned u = __builtin_bit_cast(unsigned, x);
    u += 0x7fffu + ((u >> 16) & 1u);
    return (unsigned short)(u >> 16);
}
__device__ __forceinline__ float bf16_to_f32(unsigned short h) {
    unsigned u = ((unsigned)h) << 16;
    return __builtin_bit_cast(float, u);
}

// ---------------------------------------------------------------------------
// Phase 1: split-fp16 MFMA transition GEMMs
//   C = act(A @ W^T + bias [+ resid]),  A = Ahi+Alo (fp16 pair, [M][K]),
//   W = Whi+Wlo (fp16 pair, [N][K] row-major = transposed weight).
//   3-pass: Ahi*Whi + Ahi*Wlo + Alo*Whi accumulated in f32.
// Tile: BMT x 128, 512 threads (8 waves as 2x4), K-step 32.
// ---------------------------------------------------------------------------
template <int BMT, bool WRITE_SPLIT, bool RELU, bool RESID>
__global__ __launch_bounds__(512) void trans_gemm(
    const _Float16* __restrict__ Ahi, const _Float16* __restrict__ Alo, int K,
    const _Float16* __restrict__ Whi, const _Float16* __restrict__ Wlo,
    const float* __restrict__ bias,
    const float* __restrict__ resid, int ldr,
    _Float16* __restrict__ Ohi, _Float16* __restrict__ Olo,
    float* __restrict__ Of, int ldo)
{
    __shared__ _Float16 Ah[BMT][40];
    __shared__ _Float16 Al[BMT][40];
    __shared__ _Float16 Bh[128][40];
    __shared__ _Float16 Bl[128][40];

    const int tid = threadIdx.x;
    const int m0 = blockIdx.y * BMT;
    const int n0 = blockIdx.x * 128;
    const int w = tid >> 6, l = tid & 63;
    const int wm = w >> 2, wn = w & 3;          // 2 x 4 waves
    const int kg = l >> 4, lr = l & 15;
    constexpr int AF = BMT / 32;                 // A-frags per wave

    f32x4 acc[AF][2] = {};

    for (int k0 = 0; k0 < K; k0 += 32) {
        // stage A (BMT rows x 32 halves, hi+lo)
        if (BMT == 128 || tid < 256) {
            int row = tid >> 2;
            int ch = tid & 3;
            size_t src = (size_t)(m0 + row) * K + k0 + ch * 8;
            *reinterpret_cast<f16x8*>(&Ah[row][ch * 8]) =
                *reinterpret_cast<const f16x8*>(&Ahi[src]);
            *reinterpret_cast<f16x8*>(&Al[row][ch * 8]) =
                *reinterpret_cast<const f16x8*>(&Alo[src]);
        }
        // stage B (128 n-rows x 32 halves, hi+lo)
        {
            int row = tid >> 2;
            int ch = tid & 3;
            size_t src = (size_t)(n0 + row) * K + k0 + ch * 8;
            *reinterpret_cast<f16x8*>(&Bh[row][ch * 8]) =
                *reinterpret_cast<const f16x8*>(&Whi[src]);
            *reinterpret_cast<f16x8*>(&Bl[row][ch * 8]) =
                *reinterpret_cast<const f16x8*>(&Wlo[src]);
        }
        __syncthreads();

        f16x8 ah[AF], al[AF], bh[2], bl[2];
#pragma unroll
        for (int i = 0; i < AF; ++i) {
            int r = wm * (BMT / 2) + i * 16 + lr;
            ah[i] = *reinterpret_cast<const f16x8*>(&Ah[r][kg * 8]);
            al[i] = *reinterpret_cast<const f16x8*>(&Al[r][kg * 8]);
        }
#pragma unroll
        for (int j = 0; j < 2; ++j) {
            int r = wn * 32 + j * 16 + lr;
            bh[j] = *reinterpret_cast<const f16x8*>(&Bh[r][kg * 8]);
            bl[j] = *reinterpret_cast<const f16x8*>(&Bl[r][kg * 8]);
        }
#pragma unroll
        for (int i = 0; i < AF; ++i)
#pragma unroll
            for (int j = 0; j < 2; ++j) {
                acc[i][j] = __builtin_amdgcn_mfma_f32_16x16x32_f16(
                    ah[i], bh[j], acc[i][j], 0, 0, 0);
                acc[i][j] = __builtin_amdgcn_mfma_f32_16x16x32_f16(
                    ah[i], bl[j], acc[i][j], 0, 0, 0);
                acc[i][j] = __builtin_amdgcn_mfma_f32_16x16x32_f16(
                    al[i], bh[j], acc[i][j], 0, 0, 0);
            }
        __syncthreads();
    }

    float bv[2];
#pragma unroll
    for (int j = 0; j < 2; ++j) bv[j] = bias[n0 + wn * 32 + j * 16 + lr];

#pragma unroll
    for (int i = 0; i < AF; ++i)
#pragma unroll
        for (int j = 0; j < 2; ++j)
#pragma unroll
            for (int r = 0; r < 4; ++r) {
                int row = m0 + wm * (BMT / 2) + i * 16 + kg * 4 + r;
                int col = n0 + wn * 32 + j * 16 + lr;
                float v = acc[i][j][r] + bv[j];
                if (RESID)
                    v += resid[(size_t)row * ldr + col];
                if (RELU) v = fmaxf(v, 0.f);
                if (WRITE_SPLIT) {
                    _Float16 h = (_Float16)v;
                    Ohi[(size_t)row * ldo + col] = h;
                    Olo[(size_t)row * ldo + col] = (_Float16)(v - (float)h);
                } else {
                    Of[(size_t)row * ldo + col] = v;
                }
            }
}

// W [K][N] f32 -> Whi/Wlo [N][K] fp16 split (once per call)
__global__ __launch_bounds__(256) void split_transpose(
    const float* __restrict__ W, _Float16* __restrict__ Whi,
    _Float16* __restrict__ Wlo, int K, int N)
{
    int k = blockIdx.x * 256 + threadIdx.x;
    int n = blockIdx.y;
    if (k < K) {
        float v = W[(size_t)k * N + n];
        _Float16 h = (_Float16)v;
        Whi[(size_t)n * K + k] = h;
        Wlo[(size_t)n * K + k] = (_Float16)(v - (float)h);
    }
}

// Build sae = [state, action@Wae+bae] for step t, output as fp16 hi/lo.
__global__ __launch_bounds__(576) void prep_split(
    const float* __restrict__ states,   // [B][33][512]
    int t,
    const float* __restrict__ actions,  // [B][32][64]
    const float* __restrict__ Wae,      // [64][64]
    const float* __restrict__ bae,      // [64]
    _Float16* __restrict__ saeh,        // [B][576]
    _Float16* __restrict__ sael)        // [B][576]
{
    const int b = blockIdx.x;
    const int tid = threadIdx.x;
    float v;
    if (tid < L_) {
        v = states[(size_t)b * (33 * L_) + (size_t)t * L_ + tid];
    } else {
        int c = tid - L_;
        const float* arow = actions + (size_t)b * (HOR_ * A_) + (size_t)t * A_;
        float acc = bae[c];
#pragma unroll 8
        for (int k = 0; k < A_; ++k)
            acc = fmaf(arow[k], Wae[k * A_ + c], acc);
        v = acc;
    }
    _Float16 h = (_Float16)v;
    saeh[(size_t)b * 576 + tid] = h;
    sael[(size_t)b * 576 + tid] = (_Float16)(v - (float)h);
}

// states[:, 0, :] = initial_state
__global__ __launch_bounds__(256) void init_states_kernel(
    const float* __restrict__ init, float* __restrict__ states)
{
    long i = (long)blockIdx.x * 256 + threadIdx.x;
    long b = i >> 9;
    long l = i & 511;
    states[b * (33 * L_) + l] = init[i];
}

// ---------------- Phase 2: batched bf16 MFMA (obs + harm paths) -------------

// WT[n][k] = bf16(W[k][n])
__global__ __launch_bounds__(256) void cast_transpose(
    const float* __restrict__ W, ushort_t* __restrict__ WT, int K, int N)
{
    int k = blockIdx.x * 256 + threadIdx.x;
    int n = blockIdx.y;
    if (k < K) WT[(long)n * K + k] = bf16_rne(W[(long)k * N + n]);
}

// Out[m][n] (bf16) = relu( A[m][:] @ WT^T + bias ), A f32 with hi/lo split.
__global__ __launch_bounds__(256) void mm_split(
    const float* __restrict__ Astate,  // chunk base of states [..][33][512]
    const float* __restrict__ Aact,    // chunk base of actions [CB*32][64]
    int Ktot,                          // 512 or 576
    const ushort_t* __restrict__ WT,   // [N][Ktot] bf16
    int N,
    const float* __restrict__ bias,
    ushort_t* __restrict__ Out)        // [MC][N] bf16
{
    __shared__ ushort_t Ahi[128][40];
    __shared__ ushort_t Alo[128][40];
    __shared__ ushort_t Bt[128][40];

    const int tid = threadIdx.x;
    const int m0 = blockIdx.y * 128;
    const int n0 = blockIdx.x * 128;
    const int w = tid >> 6;
    const int l = tid & 63;
    const int wm = w >> 1, wn = w & 1;
    const int kg = l >> 4, lr = l & 15;

    f32x4 acc[4][4] = {};

    for (int k0 = 0; k0 < Ktot; k0 += 32) {
#pragma unroll
        for (int s = 0; s < 4; ++s) {
            int idx = tid + s * 256;
            int arow = idx >> 3;
            int ch = idx & 7;
            int m = m0 + arow;
            const float* src;
            if (k0 < L_) {
                src = Astate + (long)((m >> 5) * 33 + (m & 31)) * L_ + k0 + ch * 4;
            } else {
                src = Aact + (long)m * A_ + (k0 - L_) + ch * 4;
            }
            float4 v = *reinterpret_cast<const float4*>(src);
            unsigned short h0 = bf16_rne(v.x), h1 = bf16_rne(v.y),
                           h2 = bf16_rne(v.z), h3 = bf16_rne(v.w);
            unsigned short e0 = bf16_rne(v.x - bf16_to_f32(h0));
            unsigned short e1 = bf16_rne(v.y - bf16_to_f32(h1));
            unsigned short e2 = bf16_rne(v.z - bf16_to_f32(h2));
            unsigned short e3 = bf16_rne(v.w - bf16_to_f32(h3));
            s16x4 hv = {(short)h0, (short)h1, (short)h2, (short)h3};
            s16x4 lv = {(short)e0, (short)e1, (short)e2, (short)e3};
            *reinterpret_cast<s16x4*>(&Ahi[arow][ch * 4]) = hv;
            *reinterpret_cast<s16x4*>(&Alo[arow][ch * 4]) = lv;
        }
#pragma unroll
        for (int s = 0; s < 2; ++s) {
            int idx = tid + s * 256;
            int brow = idx >> 2;
            int ch = idx & 3;
            s16x8 wv = *reinterpret_cast<const s16x8*>(
                &WT[(long)(n0 + brow) * Ktot + k0 + ch * 8]);
            *reinterpret_cast<s16x8*>(&Bt[brow][ch * 8]) = wv;
        }
        __syncthreads();

        s16x8 ah[4], al[4], bb[4];
#pragma unroll
        for (int i = 0; i < 4; ++i) {
            int r = wm * 64 + i * 16 + lr;
            ah[i] = *reinterpret_cast<const s16x8*>(&Ahi[r][kg * 8]);
            al[i] = *reinterpret_cast<const s16x8*>(&Alo[r][kg * 8]);
        }
#pragma unroll
        for (int j = 0; j < 4; ++j) {
            int r = wn * 64 + j * 16 + lr;
            bb[j] = *reinterpret_cast<const s16x8*>(&Bt[r][kg * 8]);
        }
#pragma unroll
        for (int i = 0; i < 4; ++i)
#pragma unroll
            for (int j = 0; j < 4; ++j) {
                acc[i][j] = __builtin_amdgcn_mfma_f32_16x16x32_bf16(
                    ah[i], bb[j], acc[i][j], 0, 0, 0);
                acc[i][j] = __builtin_amdgcn_mfma_f32_16x16x32_bf16(
                    al[i], bb[j], acc[i][j], 0, 0, 0);
            }
        __syncthreads();
    }

    float bv[4];
#pragma unroll
    for (int j = 0; j < 4; ++j) bv[j] = bias[n0 + wn * 64 + j * 16 + lr];
#pragma unroll
    for (int i = 0; i < 4; ++i)
#pragma unroll
        for (int j = 0; j < 4; ++j)
#pragma unroll
            for (int r = 0; r < 4; ++r) {
                int row = m0 + wm * 64 + i * 16 + kg * 4 + r;
                int col = n0 + wn * 64 + j * 16 + lr;
                float v = fmaxf(acc[i][j][r] + bv[j], 0.f);
                Out[(long)row * N + col] = bf16_rne(v);
            }
}

// Out[m][n] (f32) = A_bf16[m][:] @ WT^T + bias   (K = 1024, no relu)
__global__ __launch_bounds__(256) void mm_bf16(
    const ushort_t* __restrict__ Abf,  // [MC][1024] bf16
    const ushort_t* __restrict__ WT,   // [N][1024] bf16
    int N,
    const float* __restrict__ bias,
    float* __restrict__ Out)           // [MC][N] f32
{
    __shared__ ushort_t At[128][40];
    __shared__ ushort_t Bt[128][40];

    const int tid = threadIdx.x;
    const int m0 = blockIdx.y * 128;
    const int n0 = blockIdx.x * 128;
    const int w = tid >> 6;
    const int l = tid & 63;
    const int wm = w >> 1, wn = w & 1;
    const int kg = l >> 4, lr = l & 15;

    f32x4 acc[4][4] = {};

    for (int k0 = 0; k0 < HID_; k0 += 32) {
#pragma unroll
        for (int s = 0; s < 2; ++s) {
            int idx = tid + s * 256;
            int arow = idx >> 2;
            int ch = idx & 3;
            s16x8 av = *reinterpret_cast<const s16x8*>(
                &Abf[(long)(m0 + arow) * HID_ + k0 + ch * 8]);
            *reinterpret_cast<s16x8*>(&At[arow][ch * 8]) = av;
        }
#pragma unroll
        for (int s = 0; s < 2; ++s) {
            int idx = tid + s * 256;
            int brow = idx >> 2;
            int ch = idx & 3;
            s16x8 wv = *reinterpret_cast<const s16x8*>(
                &WT[(long)(n0 + brow) * HID_ + k0 + ch * 8]);
            *reinterpret_cast<s16x8*>(&Bt[brow][ch * 8]) = wv;
        }
        __syncthreads();

        s16x8 aa[4], bb[4];
#pragma unroll
        for (int i = 0; i < 4; ++i)
            aa[i] = *reinterpret_cast<const s16x8*>(&At[wm * 64 + i * 16 + lr][kg * 8]);
#pragma unroll
        for (int j = 0; j < 4; ++j)
            bb[j] = *reinterpret_cast<const s16x8*>(&Bt[wn * 64 + j * 16 + lr][kg * 8]);
#pragma unroll
        for (int i = 0; i < 4; ++i)
#pragma unroll
            for (int j = 0; j < 4; ++j)
                acc[i][j] = __builtin_amdgcn_mfma_f32_16x16x32_bf16(
                    aa[i], bb[j], acc[i][j], 0, 0, 0);
        __syncthreads();
    }

    float bv[4];
#pragma unroll
    for (int j = 0; j < 4; ++j) bv[j] = bias[n0 + wn * 64 + j * 16 + lr];
#pragma unroll
    for (int i = 0; i < 4; ++i)
#pragma unroll
        for (int j = 0; j < 4; ++j)
#pragma unroll
            for (int r = 0; r < 4; ++r) {
                int row = m0 + wm * 64 + i * 16 + kg * 4 + r;
                int col = n0 + wn * 64 + j * 16 + lr;
                Out[(long)row * N + col] = acc[i][j][r] + bv[j];
            }
}

// harm[m] = sigmoid(hh[m][:] . Wh2 + bh2), one wave per row.
__global__ __launch_bounds__(256) void harm_reduce(
    const ushort_t* __restrict__ hh,  // [MC][1024] bf16
    const float* __restrict__ Wh2,    // [1024]
    const float* __restrict__ bh2,
    float* __restrict__ harm)
{
    const int wave = threadIdx.x >> 6;
    const int lane = threadIdx.x & 63;
    const long r = (long)blockIdx.x * 4 + wave;
    const ushort_t* row = hh + r * HID_;
    float s = 0.f;
#pragma unroll
    for (int q = 0; q < 2; ++q) {
        s16x8 a = *reinterpret_cast<const s16x8*>(&row[lane * 16 + q * 8]);
        float4 w0 = *reinterpret_cast<const float4*>(&Wh2[lane * 16 + q * 8]);
        float4 w1 = *reinterpret_cast<const float4*>(&Wh2[lane * 16 + q * 8 + 4]);
        s = fmaf(bf16_to_f32((unsigned short)a[0]), w0.x, s);
        s = fmaf(bf16_to_f32((unsigned short)a[1]), w0.y, s);
        s = fmaf(bf16_to_f32((unsigned short)a[2]), w0.z, s);
        s = fmaf(bf16_to_f32((unsigned short)a[3]), w0.w, s);
        s = fmaf(bf16_to_f32((unsigned short)a[4]), w1.x, s);
        s = fmaf(bf16_to_f32((unsigned short)a[5]), w1.y, s);
        s = fmaf(bf16_to_f32((unsigned short)a[6]), w1.z, s);
        s = fmaf(bf16_to_f32((unsigned short)a[7]), w1.w, s);
    }
#pragma unroll
    for (int off = 32; off; off >>= 1) s += __shfl_down(s, off);
    if (lane == 0) {
        float x = s + bh2[0];
        harm[r] = 1.f / (1.f + expf(-x));
    }
}

// ---------------------------------------------------------------------------
extern "C" void kernel_launch(void* const* d_in, const int* in_sizes, int n_in,
                              void* d_out, int out_size, void* d_ws, size_t ws_size,
                              hipStream_t stream)
{
    const float* initial = (const float*)d_in[0];
    const float* actions = (const float*)d_in[1];
    const float* Wae = (const float*)d_in[2];
    const float* bae = (const float*)d_in[3];
    const float* Wt1 = (const float*)d_in[4];
    const float* bt1 = (const float*)d_in[5];
    const float* Wt2 = (const float*)d_in[6];
    const float* bt2 = (const float*)d_in[7];
    const float* Wt3 = (const float*)d_in[8];
    const float* bt3 = (const float*)d_in[9];
    const float* Wo1 = (const float*)d_in[10];
    const float* bo1 = (const float*)d_in[11];
    const float* Wo2 = (const float*)d_in[12];
    const float* bo2 = (const float*)d_in[13];
    const float* Wh1 = (const float*)d_in[14];
    const float* bh1 = (const float*)d_in[15];
    const float* Wh2 = (const float*)d_in[16];
    const float* bh2 = (const float*)d_in[17];

    float* out = (float*)d_out;
    float* states = out;                                    // [B][33][512]
    float* obs = out + (size_t)B_ * 33 * L_;                // [B][32][512]
    float* harm = obs + (size_t)B_ * HOR_ * L_;             // [B][32]

    // ws layout
    char* p = (char*)d_ws;
    ushort_t* WT_o1 = (ushort_t*)p; p += (size_t)HID_ * L_ * 2;     // [1024][512]
    ushort_t* WT_o2 = (ushort_t*)p; p += (size_t)L_ * HID_ * 2;     // [512][1024]
    ushort_t* WT_h1 = (ushort_t*)p; p += (size_t)HID_ * 576 * 2;    // [1024][576]
    _Float16* Wt1h = (_Float16*)p;  p += (size_t)HID_ * 576 * 2;    // [1024][576]
    _Float16* Wt1l = (_Float16*)p;  p += (size_t)HID_ * 576 * 2;
    _Float16* Wt2h = (_Float16*)p;  p += (size_t)HID_ * HID_ * 2;   // [1024][1024]
    _Float16* Wt2l = (_Float16*)p;  p += (size_t)HID_ * HID_ * 2;
    _Float16* Wt3h = (_Float16*)p;  p += (size_t)L_ * HID_ * 2;     // [512][1024]
    _Float16* Wt3l = (_Float16*)p;  p += (size_t)L_ * HID_ * 2;
    _Float16* saeh = (_Float16*)p;  p += (size_t)B_ * 576 * 2;      // [B][576]
    _Float16* sael = (_Float16*)p;  p += (size_t)B_ * 576 * 2;
    _Float16* h1h  = (_Float16*)p;  p += (size_t)B_ * HID_ * 2;     // [B][1024]
    _Float16* h1l  = (_Float16*)p;  p += (size_t)B_ * HID_ * 2;
    _Float16* h2h  = (_Float16*)p;  p += (size_t)B_ * HID_ * 2;
    _Float16* h2l  = (_Float16*)p;  p += (size_t)B_ * HID_ * 2;
    // phase-2 activation buffer reuses the h1/h2 region (16M halves each)
    ushort_t* oh = (ushort_t*)h1h;                                  // [MC][1024]

    // one-time weight prep
    cast_transpose<<<dim3(2, HID_), 256, 0, stream>>>(Wo1, WT_o1, L_, HID_);
    cast_transpose<<<dim3(4, L_), 256, 0, stream>>>(Wo2, WT_o2, HID_, L_);
    cast_transpose<<<dim3(3, HID_), 256, 0, stream>>>(Wh1, WT_h1, 576, HID_);
    split_transpose<<<dim3(3, HID_), 256, 0, stream>>>(Wt1, Wt1h, Wt1l, 576, HID_);
    split_transpose<<<dim3(4, HID_), 256, 0, stream>>>(Wt2, Wt2h, Wt2l, HID_, HID_);
    split_transpose<<<dim3(4, L_), 256, 0, stream>>>(Wt3, Wt3h, Wt3l, HID_, L_);

    init_states_kernel<<<(B_ * L_) / 256, 256, 0, stream>>>(initial, states);

    const int ldS = 33 * L_;

    // ---- Phase 1: serial transition rollout (split-fp16 MFMA) ----
    for (int t = 0; t < HOR_; ++t) {
        const float* st = states + (long)t * L_;
        prep_split<<<B_, 576, 0, stream>>>(states, t, actions, Wae, bae, saeh, sael);
        // h1 = relu(sae @ Wt1 + bt1) -> fp16 hi/lo
        trans_gemm<128, true, true, false><<<dim3(HID_ / 128, B_ / 128), 512, 0, stream>>>(
            saeh, sael, 576, Wt1h, Wt1l, bt1, nullptr, 0, h1h, h1l, nullptr, HID_);
        // h2 = relu(h1 @ Wt2 + bt2) -> fp16 hi/lo
        trans_gemm<128, true, true, false><<<dim3(HID_ / 128, B_ / 128), 512, 0, stream>>>(
            h1h, h1l, HID_, Wt2h, Wt2l, bt2, nullptr, 0, h2h, h2l, nullptr, HID_);
        // next_state = state + h2 @ Wt3 + bt3 -> f32 (BM=64 for 256 blocks)
        trans_gemm<64, false, false, true><<<dim3(L_ / 128, B_ / 64), 512, 0, stream>>>(
            h2h, h2l, HID_, Wt3h, Wt3l, bt3, st, ldS, nullptr, nullptr,
            states + (long)(t + 1) * L_, ldS);
    }

    // ---- Phase 2: batched obs + harm in bf16 MFMA, 8 chunks of 512 batch ----
    for (int c = 0; c < B_ / CB; ++c) {
        const float* Sc = states + (size_t)c * CB * 33 * L_;
        const float* Ac = actions + (size_t)c * CB * HOR_ * A_;
        mm_split<<<dim3(HID_ / 128, MC / 128), 256, 0, stream>>>(
            Sc, nullptr, L_, WT_o1, HID_, bo1, oh);
        mm_bf16<<<dim3(L_ / 128, MC / 128), 256, 0, stream>>>(
            oh, WT_o2, L_, bo2, obs + (size_t)c * CB * HOR_ * L_);
        mm_split<<<dim3(HID_ / 128, MC / 128), 256, 0, stream>>>(
            Sc, Ac, 576, WT_h1, HID_, bh1, oh);
        harm_reduce<<<MC / 4, 256, 0, stream>>>(
            oh, Wh2, bh2, harm + (size_t)c * CB * HOR_);
    }
}

// Round 4
// 4427.855 us; speedup vs baseline: 3.8194x; 1.2893x over previous
//
#include <hip/hip_runtime.h>
#include <math.h>

// Problem dims
#define B_ 4096
#define HOR_ 32
#define L_ 512
#define A_ 64
#define HID_ 1024

// phase-2 chunking
#define CB 512            // batch rows per chunk
#define MC (CB * HOR_)    // 16384 rows per chunk

typedef unsigned short ushort_t;
typedef __attribute__((ext_vector_type(4))) float f32x4;
typedef __attribute__((ext_vector_type(8))) short s16x8;
typedef __attribute__((ext_vector_type(4))) short s16x4;
typedef __attribute__((ext_vector_type(8))) _Float16 f16x8;

__device__ __forceinline__ unsigned short bf16_rne(float x) {
    unsigned u = __builtin_bit_cast(unsigned, x);
    u += 0x7fffu + ((u >> 16) & 1u);
    return (unsigned short)(u >> 16);
}
__device__ __forceinline__ float bf16_to_f32(unsigned short h) {
    unsigned u = ((unsigned)h) << 16;
    return __builtin_bit_cast(float, u);
}

// ---------------------------------------------------------------------------
// Phase 1: split-fp16 MFMA transition GEMMs.
//   C = act(A @ W^T + bias [+ resid]);  A = Ahi+Alo fp16 pair.
//   TWOSRC: A cols [0,512) from Ahi/Alo (stride lda), cols [512,K) from f32
//   Aae (split on the fly).
//   3-pass: Ahi*Whi + Ahi*Wlo + Alo*Whi, f32 accum.
//   Register-prefetch + double-buffered LDS, ONE barrier per K-step.
// ---------------------------------------------------------------------------
template <int BMT, bool TWOSRC, bool SPLIT_OUT, bool RELU, bool RESID, bool F32OUT>
__global__ __launch_bounds__(512, 4) void trans_gemm(
    const _Float16* __restrict__ Ahi, const _Float16* __restrict__ Alo,
    int lda, int K,
    const float* __restrict__ Aae, int lda_ae, int aoff,
    const _Float16* __restrict__ Whi, const _Float16* __restrict__ Wlo,
    const float* __restrict__ bias,
    const float* __restrict__ resid, int ldr,
    _Float16* __restrict__ Ohi, _Float16* __restrict__ Olo, int ldoh,
    float* __restrict__ Of, int ldof)
{
    __shared__ _Float16 Ah[2][BMT][40];
    __shared__ _Float16 Al[2][BMT][40];
    __shared__ _Float16 Bh[2][128][40];
    __shared__ _Float16 Bl[2][128][40];

    const int tid = threadIdx.x;
    const int m0 = blockIdx.y * BMT;
    const int n0 = blockIdx.x * 128;
    const int w = tid >> 6, l = tid & 63;
    const int wm = w >> 2, wn = w & 3;          // 2 x 4 waves
    const int kg = l >> 4, lr = l & 15;
    constexpr int AF = BMT / 32;                 // A-frags per wave

    const int srow = tid >> 2, sg = tid & 3;     // staging row / 16B granule
    const bool doA = (BMT == 128) || (tid < 256);

    f32x4 acc[AF][2] = {};
    f16x8 rAh, rAl, rBh, rBl;

    const _Float16* pBh = Whi + (size_t)(n0 + srow) * K + sg * 8;
    const _Float16* pBl = Wlo + (size_t)(n0 + srow) * K + sg * 8;
    const _Float16* pAh = Ahi + (size_t)(m0 + (doA ? srow : 0)) * lda + sg * 8;
    const _Float16* pAl = Alo + (size_t)(m0 + (doA ? srow : 0)) * lda + sg * 8;
    const float* pAe = TWOSRC
        ? (Aae + (size_t)(m0 + (doA ? srow : 0)) * lda_ae + aoff + sg * 8)
        : nullptr;

    auto load_regs = [&](int ks) {
        const int k0 = ks * 32;
        rBh = *reinterpret_cast<const f16x8*>(pBh + k0);
        rBl = *reinterpret_cast<const f16x8*>(pBl + k0);
        if (doA) {
            if (!TWOSRC || k0 < L_) {
                rAh = *reinterpret_cast<const f16x8*>(pAh + k0);
                rAl = *reinterpret_cast<const f16x8*>(pAl + k0);
            } else {
                const float* s = pAe + (k0 - L_);
                float4 v0 = *reinterpret_cast<const float4*>(s);
                float4 v1 = *reinterpret_cast<const float4*>(s + 4);
                float vv[8] = {v0.x, v0.y, v0.z, v0.w, v1.x, v1.y, v1.z, v1.w};
                f16x8 h, lo;
#pragma unroll
                for (int j = 0; j < 8; ++j) {
                    _Float16 hh = (_Float16)vv[j];
                    h[j] = hh;
                    lo[j] = (_Float16)(vv[j] - (float)hh);
                }
                rAh = h; rAl = lo;
            }
        }
    };
    auto write_lds = [&](int buf) {
        *reinterpret_cast<f16x8*>(&Bh[buf][srow][sg * 8]) = rBh;
        *reinterpret_cast<f16x8*>(&Bl[buf][srow][sg * 8]) = rBl;
        if (doA) {
            *reinterpret_cast<f16x8*>(&Ah[buf][srow][sg * 8]) = rAh;
            *reinterpret_cast<f16x8*>(&Al[buf][srow][sg * 8]) = rAl;
        }
    };

    const int NT = K / 32;
    load_regs(0);
    write_lds(0);
    __syncthreads();
    int cur = 0;

    for (int ks = 0; ks < NT; ++ks) {
        if (ks + 1 < NT) load_regs(ks + 1);   // next tile's loads in flight

        f16x8 ah[AF], al[AF], bh[2], bl[2];
#pragma unroll
        for (int i = 0; i < AF; ++i) {
            int r = wm * (BMT / 2) + i * 16 + lr;
            ah[i] = *reinterpret_cast<const f16x8*>(&Ah[cur][r][kg * 8]);
            al[i] = *reinterpret_cast<const f16x8*>(&Al[cur][r][kg * 8]);
        }
#pragma unroll
        for (int j = 0; j < 2; ++j) {
            int r = wn * 32 + j * 16 + lr;
            bh[j] = *reinterpret_cast<const f16x8*>(&Bh[cur][r][kg * 8]);
            bl[j] = *reinterpret_cast<const f16x8*>(&Bl[cur][r][kg * 8]);
        }
#pragma unroll
        for (int i = 0; i < AF; ++i)
#pragma unroll
            for (int j = 0; j < 2; ++j) {
                acc[i][j] = __builtin_amdgcn_mfma_f32_16x16x32_f16(
                    ah[i], bh[j], acc[i][j], 0, 0, 0);
                acc[i][j] = __builtin_amdgcn_mfma_f32_16x16x32_f16(
                    ah[i], bl[j], acc[i][j], 0, 0, 0);
                acc[i][j] = __builtin_amdgcn_mfma_f32_16x16x32_f16(
                    al[i], bh[j], acc[i][j], 0, 0, 0);
            }

        if (ks + 1 < NT) {
            write_lds(cur ^ 1);
            __syncthreads();
            cur ^= 1;
        }
    }

    float bv[2];
#pragma unroll
    for (int j = 0; j < 2; ++j) bv[j] = bias[n0 + wn * 32 + j * 16 + lr];

#pragma unroll
    for (int i = 0; i < AF; ++i)
#pragma unroll
        for (int j = 0; j < 2; ++j)
#pragma unroll
            for (int r = 0; r < 4; ++r) {
                int row = m0 + wm * (BMT / 2) + i * 16 + kg * 4 + r;
                int col = n0 + wn * 32 + j * 16 + lr;
                float v = acc[i][j][r] + bv[j];
                if (RESID)
                    v += resid[(size_t)row * ldr + col];
                if (RELU) v = fmaxf(v, 0.f);
                if (F32OUT)
                    Of[(size_t)row * ldof + col] = v;
                if (SPLIT_OUT) {
                    _Float16 h = (_Float16)v;
                    Ohi[(size_t)row * ldoh + col] = h;
                    Olo[(size_t)row * ldoh + col] = (_Float16)(v - (float)h);
                }
            }
}

// W [K][N] f32 -> Whi/Wlo [N][K] fp16 split (once per call)
__global__ __launch_bounds__(256) void split_transpose(
    const float* __restrict__ W, _Float16* __restrict__ Whi,
    _Float16* __restrict__ Wlo, int K, int N)
{
    int k = blockIdx.x * 256 + threadIdx.x;
    int n = blockIdx.y;
    if (k < K) {
        float v = W[(size_t)k * N + n];
        _Float16 h = (_Float16)v;
        Whi[(size_t)n * K + k] = h;
        Wlo[(size_t)n * K + k] = (_Float16)(v - (float)h);
    }
}

// ae[b,t,:] = action[b,t] @ Wae + bae  for ALL (b,t); one wave per row.
__global__ __launch_bounds__(256) void ae_all(
    const float* __restrict__ actions,  // [B*HOR][64]
    const float* __restrict__ Wae,      // [64][64]
    const float* __restrict__ bae,      // [64]
    float* __restrict__ ae)             // [B*HOR][64]
{
    const long r = (long)blockIdx.x * 4 + (threadIdx.x >> 6);
    const int c = threadIdx.x & 63;
    const float* arow = actions + r * 64;
    float acc = bae[c];
#pragma unroll 16
    for (int k = 0; k < 64; ++k) acc = fmaf(arow[k], Wae[k * 64 + c], acc);
    ae[r * 64 + c] = acc;
}

// fallback: ae for one step t -> aeS [B][64]
__global__ __launch_bounds__(256) void ae_step(
    const float* __restrict__ actions, const float* __restrict__ Wae,
    const float* __restrict__ bae, int t, float* __restrict__ aeS)
{
    const long b = (long)blockIdx.x * 4 + (threadIdx.x >> 6);
    const int c = threadIdx.x & 63;
    const float* arow = actions + (b * HOR_ + t) * 64;
    float acc = bae[c];
#pragma unroll 16
    for (int k = 0; k < 64; ++k) acc = fmaf(arow[k], Wae[k * 64 + c], acc);
    aeS[b * 64 + c] = acc;
}

// states[:,0,:] = initial; sth/stl = split(initial)
__global__ __launch_bounds__(256) void init_split(
    const float* __restrict__ init, float* __restrict__ states,
    _Float16* __restrict__ sth, _Float16* __restrict__ stl)
{
    size_t i = (size_t)blockIdx.x * 256 + threadIdx.x;   // over B*L
    size_t b = i >> 9, l = i & 511;
    float v = init[i];
    states[b * (33 * L_) + l] = v;
    _Float16 h = (_Float16)v;
    sth[i] = h;
    stl[i] = (_Float16)(v - (float)h);
}

// ---------------- Phase 2: batched bf16 MFMA (obs + harm paths) -------------

// WT[n][k] = bf16(W[k][n])
__global__ __launch_bounds__(256) void cast_transpose(
    const float* __restrict__ W, ushort_t* __restrict__ WT, int K, int N)
{
    int k = blockIdx.x * 256 + threadIdx.x;
    int n = blockIdx.y;
    if (k < K) WT[(long)n * K + k] = bf16_rne(W[(long)k * N + n]);
}

// Out[m][n] (bf16) = relu( A[m][:] @ WT^T + bias ), A f32 with hi/lo split.
__global__ __launch_bounds__(256) void mm_split(
    const float* __restrict__ Astate,  // chunk base of states [..][33][512]
    const float* __restrict__ Aact,    // chunk base of actions [CB*32][64]
    int Ktot,                          // 512 or 576
    const ushort_t* __restrict__ WT,   // [N][Ktot] bf16
    int N,
    const float* __restrict__ bias,
    ushort_t* __restrict__ Out)        // [MC][N] bf16
{
    __shared__ ushort_t Ahi[128][40];
    __shared__ ushort_t Alo[128][40];
    __shared__ ushort_t Bt[128][40];

    const int tid = threadIdx.x;
    const int m0 = blockIdx.y * 128;
    const int n0 = blockIdx.x * 128;
    const int w = tid >> 6;
    const int l = tid & 63;
    const int wm = w >> 1, wn = w & 1;
    const int kg = l >> 4, lr = l & 15;

    f32x4 acc[4][4] = {};

    for (int k0 = 0; k0 < Ktot; k0 += 32) {
#pragma unroll
        for (int s = 0; s < 4; ++s) {
            int idx = tid + s * 256;
            int arow = idx >> 3;
            int ch = idx & 7;
            int m = m0 + arow;
            const float* src;
            if (k0 < L_) {
                src = Astate + (long)((m >> 5) * 33 + (m & 31)) * L_ + k0 + ch * 4;
            } else {
                src = Aact + (long)m * A_ + (k0 - L_) + ch * 4;
            }
            float4 v = *reinterpret_cast<const float4*>(src);
            unsigned short h0 = bf16_rne(v.x), h1 = bf16_rne(v.y),
                           h2 = bf16_rne(v.z), h3 = bf16_rne(v.w);
            unsigned short e0 = bf16_rne(v.x - bf16_to_f32(h0));
            unsigned short e1 = bf16_rne(v.y - bf16_to_f32(h1));
            unsigned short e2 = bf16_rne(v.z - bf16_to_f32(h2));
            unsigned short e3 = bf16_rne(v.w - bf16_to_f32(h3));
            s16x4 hv = {(short)h0, (short)h1, (short)h2, (short)h3};
            s16x4 lv = {(short)e0, (short)e1, (short)e2, (short)e3};
            *reinterpret_cast<s16x4*>(&Ahi[arow][ch * 4]) = hv;
            *reinterpret_cast<s16x4*>(&Alo[arow][ch * 4]) = lv;
        }
#pragma unroll
        for (int s = 0; s < 2; ++s) {
            int idx = tid + s * 256;
            int brow = idx >> 2;
            int ch = idx & 3;
            s16x8 wv = *reinterpret_cast<const s16x8*>(
                &WT[(long)(n0 + brow) * Ktot + k0 + ch * 8]);
            *reinterpret_cast<s16x8*>(&Bt[brow][ch * 8]) = wv;
        }
        __syncthreads();

        s16x8 ah[4], al[4], bb[4];
#pragma unroll
        for (int i = 0; i < 4; ++i) {
            int r = wm * 64 + i * 16 + lr;
            ah[i] = *reinterpret_cast<const s16x8*>(&Ahi[r][kg * 8]);
            al[i] = *reinterpret_cast<const s16x8*>(&Alo[r][kg * 8]);
        }
#pragma unroll
        for (int j = 0; j < 4; ++j) {
            int r = wn * 64 + j * 16 + lr;
            bb[j] = *reinterpret_cast<const s16x8*>(&Bt[r][kg * 8]);
        }
#pragma unroll
        for (int i = 0; i < 4; ++i)
#pragma unroll
            for (int j = 0; j < 4; ++j) {
                acc[i][j] = __builtin_amdgcn_mfma_f32_16x16x32_bf16(
                    ah[i], bb[j], acc[i][j], 0, 0, 0);
                acc[i][j] = __builtin_amdgcn_mfma_f32_16x16x32_bf16(
                    al[i], bb[j], acc[i][j], 0, 0, 0);
            }
        __syncthreads();
    }

    float bv[4];
#pragma unroll
    for (int j = 0; j < 4; ++j) bv[j] = bias[n0 + wn * 64 + j * 16 + lr];
#pragma unroll
    for (int i = 0; i < 4; ++i)
#pragma unroll
        for (int j = 0; j < 4; ++j)
#pragma unroll
            for (int r = 0; r < 4; ++r) {
                int row = m0 + wm * 64 + i * 16 + kg * 4 + r;
                int col = n0 + wn * 64 + j * 16 + lr;
                float v = fmaxf(acc[i][j][r] + bv[j], 0.f);
                Out[(long)row * N + col] = bf16_rne(v);
            }
}

// Out[m][n] (f32) = A_bf16[m][:] @ WT^T + bias   (K = 1024, no relu)
__global__ __launch_bounds__(256) void mm_bf16(
    const ushort_t* __restrict__ Abf,  // [MC][1024] bf16
    const ushort_t* __restrict__ WT,   // [N][1024] bf16
    int N,
    const float* __restrict__ bias,
    float* __restrict__ Out)           // [MC][N] f32
{
    __shared__ ushort_t At[128][40];
    __shared__ ushort_t Bt[128][40];

    const int tid = threadIdx.x;
    const int m0 = blockIdx.y * 128;
    const int n0 = blockIdx.x * 128;
    const int w = tid >> 6;
    const int l = tid & 63;
    const int wm = w >> 1, wn = w & 1;
    const int kg = l >> 4, lr = l & 15;

    f32x4 acc[4][4] = {};

    for (int k0 = 0; k0 < HID_; k0 += 32) {
#pragma unroll
        for (int s = 0; s < 2; ++s) {
            int idx = tid + s * 256;
            int arow = idx >> 2;
            int ch = idx & 3;
            s16x8 av = *reinterpret_cast<const s16x8*>(
                &Abf[(long)(m0 + arow) * HID_ + k0 + ch * 8]);
            *reinterpret_cast<s16x8*>(&At[arow][ch * 8]) = av;
        }
#pragma unroll
        for (int s = 0; s < 2; ++s) {
            int idx = tid + s * 256;
            int brow = idx >> 2;
            int ch = idx & 3;
            s16x8 wv = *reinterpret_cast<const s16x8*>(
                &WT[(long)(n0 + brow) * HID_ + k0 + ch * 8]);
            *reinterpret_cast<s16x8*>(&Bt[brow][ch * 8]) = wv;
        }
        __syncthreads();

        s16x8 aa[4], bb[4];
#pragma unroll
        for (int i = 0; i < 4; ++i)
            aa[i] = *reinterpret_cast<const s16x8*>(&At[wm * 64 + i * 16 + lr][kg * 8]);
#pragma unroll
        for (int j = 0; j < 4; ++j)
            bb[j] = *reinterpret_cast<const s16x8*>(&Bt[wn * 64 + j * 16 + lr][kg * 8]);
#pragma unroll
        for (int i = 0; i < 4; ++i)
#pragma unroll
            for (int j = 0; j < 4; ++j)
                acc[i][j] = __builtin_amdgcn_mfma_f32_16x16x32_bf16(
                    aa[i], bb[j], acc[i][j], 0, 0, 0);
        __syncthreads();
    }

    float bv[4];
#pragma unroll
    for (int j = 0; j < 4; ++j) bv[j] = bias[n0 + wn * 64 + j * 16 + lr];
#pragma unroll
    for (int i = 0; i < 4; ++i)
#pragma unroll
        for (int j = 0; j < 4; ++j)
#pragma unroll
            for (int r = 0; r < 4; ++r) {
                int row = m0 + wm * 64 + i * 16 + kg * 4 + r;
                int col = n0 + wn * 64 + j * 16 + lr;
                Out[(long)row * N + col] = acc[i][j][r] + bv[j];
            }
}

// harm[m] = sigmoid(hh[m][:] . Wh2 + bh2), one wave per row.
__global__ __launch_bounds__(256) void harm_reduce(
    const ushort_t* __restrict__ hh,  // [MC][1024] bf16
    const float* __restrict__ Wh2,    // [1024]
    const float* __restrict__ bh2,
    float* __restrict__ harm)
{
    const int wave = threadIdx.x >> 6;
    const int lane = threadIdx.x & 63;
    const long r = (long)blockIdx.x * 4 + wave;
    const ushort_t* row = hh + r * HID_;
    float s = 0.f;
#pragma unroll
    for (int q = 0; q < 2; ++q) {
        s16x8 a = *reinterpret_cast<const s16x8*>(&row[lane * 16 + q * 8]);
        float4 w0 = *reinterpret_cast<const float4*>(&Wh2[lane * 16 + q * 8]);
        float4 w1 = *reinterpret_cast<const float4*>(&Wh2[lane * 16 + q * 8 + 4]);
        s = fmaf(bf16_to_f32((unsigned short)a[0]), w0.x, s);
        s = fmaf(bf16_to_f32((unsigned short)a[1]), w0.y, s);
        s = fmaf(bf16_to_f32((unsigned short)a[2]), w0.z, s);
        s = fmaf(bf16_to_f32((unsigned short)a[3]), w0.w, s);
        s = fmaf(bf16_to_f32((unsigned short)a[4]), w1.x, s);
        s = fmaf(bf16_to_f32((unsigned short)a[5]), w1.y, s);
        s = fmaf(bf16_to_f32((unsigned short)a[6]), w1.z, s);
        s = fmaf(bf16_to_f32((unsigned short)a[7]), w1.w, s);
    }
#pragma unroll
    for (int off = 32; off; off >>= 1) s += __shfl_down(s, off);
    if (lane == 0) {
        float x = s + bh2[0];
        harm[r] = 1.f / (1.f + expf(-x));
    }
}

// ---------------------------------------------------------------------------
extern "C" void kernel_launch(void* const* d_in, const int* in_sizes, int n_in,
                              void* d_out, int out_size, void* d_ws, size_t ws_size,
                              hipStream_t stream)
{
    const float* initial = (const float*)d_in[0];
    const float* actions = (const float*)d_in[1];
    const float* Wae = (const float*)d_in[2];
    const float* bae = (const float*)d_in[3];
    const float* Wt1 = (const float*)d_in[4];
    const float* bt1 = (const float*)d_in[5];
    const float* Wt2 = (const float*)d_in[6];
    const float* bt2 = (const float*)d_in[7];
    const float* Wt3 = (const float*)d_in[8];
    const float* bt3 = (const float*)d_in[9];
    const float* Wo1 = (const float*)d_in[10];
    const float* bo1 = (const float*)d_in[11];
    const float* Wo2 = (const float*)d_in[12];
    const float* bo2 = (const float*)d_in[13];
    const float* Wh1 = (const float*)d_in[14];
    const float* bh1 = (const float*)d_in[15];
    const float* Wh2 = (const float*)d_in[16];
    const float* bh2 = (const float*)d_in[17];

    float* out = (float*)d_out;
    float* states = out;                                    // [B][33][512]
    float* obs = out + (size_t)B_ * 33 * L_;                // [B][32][512]
    float* harm = obs + (size_t)B_ * HOR_ * L_;             // [B][32]

    // ws layout
    char* wsb = (char*)d_ws;
    size_t off = 0;
    auto alloc = [&](size_t bytes) { char* q = wsb + off; off += bytes; return q; };
    ushort_t* WT_o1 = (ushort_t*)alloc((size_t)HID_ * L_ * 2);
    ushort_t* WT_o2 = (ushort_t*)alloc((size_t)L_ * HID_ * 2);
    ushort_t* WT_h1 = (ushort_t*)alloc((size_t)HID_ * 576 * 2);
    _Float16* Wt1h = (_Float16*)alloc((size_t)HID_ * 576 * 2);
    _Float16* Wt1l = (_Float16*)alloc((size_t)HID_ * 576 * 2);
    _Float16* Wt2h = (_Float16*)alloc((size_t)HID_ * HID_ * 2);
    _Float16* Wt2l = (_Float16*)alloc((size_t)HID_ * HID_ * 2);
    _Float16* Wt3h = (_Float16*)alloc((size_t)L_ * HID_ * 2);
    _Float16* Wt3l = (_Float16*)alloc((size_t)L_ * HID_ * 2);
    _Float16* sth  = (_Float16*)alloc((size_t)B_ * L_ * 2);
    _Float16* stl  = (_Float16*)alloc((size_t)B_ * L_ * 2);
    _Float16* h1h  = (_Float16*)alloc((size_t)B_ * HID_ * 2);
    _Float16* h1l  = (_Float16*)alloc((size_t)B_ * HID_ * 2);
    _Float16* h2h  = (_Float16*)alloc((size_t)B_ * HID_ * 2);
    _Float16* h2l  = (_Float16*)alloc((size_t)B_ * HID_ * 2);
    float* ae = (float*)alloc(0);  // placed last; size depends on mode
    const size_t need_batched = off + (size_t)B_ * HOR_ * A_ * 4;
    const bool batched_ae = (ws_size >= need_batched);
    // fallback needs only [B][64] f32 at the same offset

    // phase-2 activation buffer overlays h1h..h2l (33.5 MB)
    ushort_t* oh = (ushort_t*)h1h;

    // one-time weight prep
    cast_transpose<<<dim3(2, HID_), 256, 0, stream>>>(Wo1, WT_o1, L_, HID_);
    cast_transpose<<<dim3(4, L_), 256, 0, stream>>>(Wo2, WT_o2, HID_, L_);
    cast_transpose<<<dim3(3, HID_), 256, 0, stream>>>(Wh1, WT_h1, 576, HID_);
    split_transpose<<<dim3(3, HID_), 256, 0, stream>>>(Wt1, Wt1h, Wt1l, 576, HID_);
    split_transpose<<<dim3(4, HID_), 256, 0, stream>>>(Wt2, Wt2h, Wt2l, HID_, HID_);
    split_transpose<<<dim3(4, L_), 256, 0, stream>>>(Wt3, Wt3h, Wt3l, HID_, L_);

    init_split<<<(B_ * L_) / 256, 256, 0, stream>>>(initial, states, sth, stl);
    if (batched_ae)
        ae_all<<<(B_ * HOR_) / 4, 256, 0, stream>>>(actions, Wae, bae, ae);

    const int ldS = 33 * L_;
    const int lda_ae = batched_ae ? (HOR_ * A_) : A_;

    // ---- Phase 1: serial transition rollout (split-fp16 MFMA) ----
    for (int t = 0; t < HOR_; ++t) {
        if (!batched_ae)
            ae_step<<<B_ / 4, 256, 0, stream>>>(actions, Wae, bae, t, ae);
        const int aoff = batched_ae ? t * A_ : 0;
        // h1 = relu([state, ae] @ Wt1^T + bt1) -> fp16 hi/lo
        trans_gemm<128, true, true, true, false, false>
            <<<dim3(HID_ / 128, B_ / 128), 512, 0, stream>>>(
            sth, stl, L_, 576, ae, lda_ae, aoff,
            Wt1h, Wt1l, bt1, nullptr, 0, h1h, h1l, HID_, nullptr, 0);
        // h2 = relu(h1 @ Wt2^T + bt2) -> fp16 hi/lo
        trans_gemm<128, false, true, true, false, false>
            <<<dim3(HID_ / 128, B_ / 128), 512, 0, stream>>>(
            h1h, h1l, HID_, HID_, nullptr, 0, 0,
            Wt2h, Wt2l, bt2, nullptr, 0, h2h, h2l, HID_, nullptr, 0);
        // next_state = state + h2 @ Wt3^T + bt3 -> f32 states AND split sth/stl
        trans_gemm<64, false, true, false, true, true>
            <<<dim3(L_ / 128, B_ / 64), 512, 0, stream>>>(
            h2h, h2l, HID_, HID_, nullptr, 0, 0,
            Wt3h, Wt3l, bt3, states + (size_t)t * L_, ldS,
            sth, stl, L_, states + (size_t)(t + 1) * L_, ldS);
    }

    // ---- Phase 2: batched obs + harm in bf16 MFMA, 8 chunks of 512 batch ----
    for (int c = 0; c < B_ / CB; ++c) {
        const float* Sc = states + (size_t)c * CB * 33 * L_;
        const float* Ac = actions + (size_t)c * CB * HOR_ * A_;
        mm_split<<<dim3(HID_ / 128, MC / 128), 256, 0, stream>>>(
            Sc, nullptr, L_, WT_o1, HID_, bo1, oh);
        mm_bf16<<<dim3(L_ / 128, MC / 128), 256, 0, stream>>>(
            oh, WT_o2, L_, bo2, obs + (size_t)c * CB * HOR_ * L_);
        mm_split<<<dim3(HID_ / 128, MC / 128), 256, 0, stream>>>(
            Sc, Ac, 576, WT_h1, HID_, bh1, oh);
        harm_reduce<<<MC / 4, 256, 0, stream>>>(
            oh, Wh2, bh2, harm + (size_t)c * CB * HOR_);
    }
}

// Round 5
// 4415.302 us; speedup vs baseline: 3.8303x; 1.0028x over previous
//
#include <hip/hip_runtime.h>
#include <math.h>

// Problem dims
#define B_ 4096
#define HOR_ 32
#define L_ 512
#define A_ 64
#define HID_ 1024

// phase-2 chunking
#define CB 512            // batch rows per chunk
#define MC (CB * HOR_)    // 16384 rows per chunk

typedef unsigned short ushort_t;
typedef __attribute__((ext_vector_type(4))) float f32x4;
typedef __attribute__((ext_vector_type(8))) short s16x8;
typedef __attribute__((ext_vector_type(4))) short s16x4;
typedef __attribute__((ext_vector_type(8))) _Float16 f16x8;

__device__ __forceinline__ unsigned short bf16_rne(float x) {
    unsigned u = __builtin_bit_cast(unsigned, x);
    u += 0x7fffu + ((u >> 16) & 1u);
    return (unsigned short)(u >> 16);
}
__device__ __forceinline__ float bf16_to_f32(unsigned short h) {
    unsigned u = ((unsigned)h) << 16;
    return __builtin_bit_cast(float, u);
}

// ---------------------------------------------------------------------------
// Phase 1: split-fp16 MFMA transition GEMMs.
//   C = act(A @ W^T + bias [+ resid]);  A = Ahi+Alo fp16 pair.
//   3-pass: Ah*Bh + Ah*Bl + Al*Bh, f32 accum. Register-prefetch +
//   double-buffered LDS, ONE barrier per K-step.
// Tile: BMT x 64, 512 threads, 8 waves as 4(M) x 2(N), wave tile (BMT/4)x32.
// Grid = (N/64) x (M/BMT) = 512 blocks -> 2 blocks/CU (LDS 40-60 KB).
// ---------------------------------------------------------------------------
template <int BMT, bool TWOSRC, bool SPLIT_OUT, bool RELU, bool RESID, bool F32OUT>
__global__ __launch_bounds__(512, 4) void trans_gemm(
    const _Float16* __restrict__ Ahi, const _Float16* __restrict__ Alo,
    int lda, int K,
    const float* __restrict__ Aae, int lda_ae, int aoff,
    const _Float16* __restrict__ Whi, const _Float16* __restrict__ Wlo,
    const float* __restrict__ bias,
    const float* __restrict__ resid, int ldr,
    _Float16* __restrict__ Ohi, _Float16* __restrict__ Olo, int ldoh,
    float* __restrict__ Of, int ldof)
{
    __shared__ _Float16 Ah[2][BMT][40];
    __shared__ _Float16 Al[2][BMT][40];
    __shared__ _Float16 Bh[2][64][40];
    __shared__ _Float16 Bl[2][64][40];

    const int tid = threadIdx.x;
    const int m0 = blockIdx.y * BMT;
    const int n0 = blockIdx.x * 64;
    const int w = tid >> 6, l = tid & 63;
    const int wr = w >> 1, wc = w & 1;           // 4 x 2 waves
    const int kg = l >> 4, lr = l & 15;
    constexpr int AF = BMT / 64;                 // A-frags per wave

    const int srow = tid >> 2, sg = tid & 3;     // staging row / 16B granule
    const bool doA = (BMT == 128) || (tid < 256);
    const bool doB = (tid < 256);

    f32x4 acc[AF][2] = {};
    f16x8 rAh, rAl, rBh, rBl;

    const _Float16* pBh = Whi + (size_t)(n0 + (doB ? srow : 0)) * K + sg * 8;
    const _Float16* pBl = Wlo + (size_t)(n0 + (doB ? srow : 0)) * K + sg * 8;
    const _Float16* pAh = Ahi + (size_t)(m0 + (doA ? srow : 0)) * lda + sg * 8;
    const _Float16* pAl = Alo + (size_t)(m0 + (doA ? srow : 0)) * lda + sg * 8;
    const float* pAe = TWOSRC
        ? (Aae + (size_t)(m0 + (doA ? srow : 0)) * lda_ae + aoff + sg * 8)
        : nullptr;

    auto load_regs = [&](int ks) {
        const int k0 = ks * 32;
        if (doB) {
            rBh = *reinterpret_cast<const f16x8*>(pBh + k0);
            rBl = *reinterpret_cast<const f16x8*>(pBl + k0);
        }
        if (doA) {
            if (!TWOSRC || k0 < L_) {
                rAh = *reinterpret_cast<const f16x8*>(pAh + k0);
                rAl = *reinterpret_cast<const f16x8*>(pAl + k0);
            } else {
                const float* s = pAe + (k0 - L_);
                float4 v0 = *reinterpret_cast<const float4*>(s);
                float4 v1 = *reinterpret_cast<const float4*>(s + 4);
                float vv[8] = {v0.x, v0.y, v0.z, v0.w, v1.x, v1.y, v1.z, v1.w};
                f16x8 h, lo;
#pragma unroll
                for (int j = 0; j < 8; ++j) {
                    _Float16 hh = (_Float16)vv[j];
                    h[j] = hh;
                    lo[j] = (_Float16)(vv[j] - (float)hh);
                }
                rAh = h; rAl = lo;
            }
        }
    };
    auto write_lds = [&](int buf) {
        if (doB) {
            *reinterpret_cast<f16x8*>(&Bh[buf][srow][sg * 8]) = rBh;
            *reinterpret_cast<f16x8*>(&Bl[buf][srow][sg * 8]) = rBl;
        }
        if (doA) {
            *reinterpret_cast<f16x8*>(&Ah[buf][srow][sg * 8]) = rAh;
            *reinterpret_cast<f16x8*>(&Al[buf][srow][sg * 8]) = rAl;
        }
    };

    const int NT = K / 32;
    load_regs(0);
    write_lds(0);
    __syncthreads();
    int cur = 0;

    for (int ks = 0; ks < NT; ++ks) {
        if (ks + 1 < NT) load_regs(ks + 1);   // next tile's loads in flight

        f16x8 ah[AF], al[AF], bh[2], bl[2];
#pragma unroll
        for (int i = 0; i < AF; ++i) {
            int r = wr * (BMT / 4) + i * 16 + lr;
            ah[i] = *reinterpret_cast<const f16x8*>(&Ah[cur][r][kg * 8]);
            al[i] = *reinterpret_cast<const f16x8*>(&Al[cur][r][kg * 8]);
        }
#pragma unroll
        for (int j = 0; j < 2; ++j) {
            int r = wc * 32 + j * 16 + lr;
            bh[j] = *reinterpret_cast<const f16x8*>(&Bh[cur][r][kg * 8]);
            bl[j] = *reinterpret_cast<const f16x8*>(&Bl[cur][r][kg * 8]);
        }
#pragma unroll
        for (int i = 0; i < AF; ++i)
#pragma unroll
            for (int j = 0; j < 2; ++j) {
                acc[i][j] = __builtin_amdgcn_mfma_f32_16x16x32_f16(
                    ah[i], bh[j], acc[i][j], 0, 0, 0);
                acc[i][j] = __builtin_amdgcn_mfma_f32_16x16x32_f16(
                    ah[i], bl[j], acc[i][j], 0, 0, 0);
                acc[i][j] = __builtin_amdgcn_mfma_f32_16x16x32_f16(
                    al[i], bh[j], acc[i][j], 0, 0, 0);
            }

        if (ks + 1 < NT) {
            write_lds(cur ^ 1);
            __syncthreads();
            cur ^= 1;
        }
    }

    float bv[2];
#pragma unroll
    for (int j = 0; j < 2; ++j) bv[j] = bias[n0 + wc * 32 + j * 16 + lr];

#pragma unroll
    for (int i = 0; i < AF; ++i)
#pragma unroll
        for (int j = 0; j < 2; ++j)
#pragma unroll
            for (int r = 0; r < 4; ++r) {
                int row = m0 + wr * (BMT / 4) + i * 16 + kg * 4 + r;
                int col = n0 + wc * 32 + j * 16 + lr;
                float v = acc[i][j][r] + bv[j];
                if (RESID)
                    v += resid[(size_t)row * ldr + col];
                if (RELU) v = fmaxf(v, 0.f);
                if (F32OUT)
                    Of[(size_t)row * ldof + col] = v;
                if (SPLIT_OUT) {
                    _Float16 h = (_Float16)v;
                    Ohi[(size_t)row * ldoh + col] = h;
                    Olo[(size_t)row * ldoh + col] = (_Float16)(v - (float)h);
                }
            }
}

// W [K][N] f32 -> Whi/Wlo [N][K] fp16 split (once per call)
__global__ __launch_bounds__(256) void split_transpose(
    const float* __restrict__ W, _Float16* __restrict__ Whi,
    _Float16* __restrict__ Wlo, int K, int N)
{
    int k = blockIdx.x * 256 + threadIdx.x;
    int n = blockIdx.y;
    if (k < K) {
        float v = W[(size_t)k * N + n];
        _Float16 h = (_Float16)v;
        Whi[(size_t)n * K + k] = h;
        Wlo[(size_t)n * K + k] = (_Float16)(v - (float)h);
    }
}

// ae[b,t,:] = action[b,t] @ Wae + bae  for ALL (b,t); one wave per row.
__global__ __launch_bounds__(256) void ae_all(
    const float* __restrict__ actions,  // [B*HOR][64]
    const float* __restrict__ Wae,      // [64][64]
    const float* __restrict__ bae,      // [64]
    float* __restrict__ ae)             // [B*HOR][64]
{
    const long r = (long)blockIdx.x * 4 + (threadIdx.x >> 6);
    const int c = threadIdx.x & 63;
    const float* arow = actions + r * 64;
    float acc = bae[c];
#pragma unroll 16
    for (int k = 0; k < 64; ++k) acc = fmaf(arow[k], Wae[k * 64 + c], acc);
    ae[r * 64 + c] = acc;
}

// fallback: ae for one step t -> aeS [B][64]
__global__ __launch_bounds__(256) void ae_step(
    const float* __restrict__ actions, const float* __restrict__ Wae,
    const float* __restrict__ bae, int t, float* __restrict__ aeS)
{
    const long b = (long)blockIdx.x * 4 + (threadIdx.x >> 6);
    const int c = threadIdx.x & 63;
    const float* arow = actions + (b * HOR_ + t) * 64;
    float acc = bae[c];
#pragma unroll 16
    for (int k = 0; k < 64; ++k) acc = fmaf(arow[k], Wae[k * 64 + c], acc);
    aeS[b * 64 + c] = acc;
}

// states[:,0,:] = initial; sth/stl = split(initial)
__global__ __launch_bounds__(256) void init_split(
    const float* __restrict__ init, float* __restrict__ states,
    _Float16* __restrict__ sth, _Float16* __restrict__ stl)
{
    size_t i = (size_t)blockIdx.x * 256 + threadIdx.x;   // over B*L
    size_t b = i >> 9, l = i & 511;
    float v = init[i];
    states[b * (33 * L_) + l] = v;
    _Float16 h = (_Float16)v;
    sth[i] = h;
    stl[i] = (_Float16)(v - (float)h);
}

// ---------------- Phase 2: batched bf16 MFMA (obs + harm paths) -------------

// WT[n][k] = bf16(W[k][n])
__global__ __launch_bounds__(256) void cast_transpose(
    const float* __restrict__ W, ushort_t* __restrict__ WT, int K, int N)
{
    int k = blockIdx.x * 256 + threadIdx.x;
    int n = blockIdx.y;
    if (k < K) WT[(long)n * K + k] = bf16_rne(W[(long)k * N + n]);
}

// Out[m][n] (bf16) = relu( A[m][:] @ WT^T + bias ), A f32 with hi/lo split.
__global__ __launch_bounds__(256) void mm_split(
    const float* __restrict__ Astate,  // chunk base of states [..][33][512]
    const float* __restrict__ Aact,    // chunk base of actions [CB*32][64]
    int Ktot,                          // 512 or 576
    const ushort_t* __restrict__ WT,   // [N][Ktot] bf16
    int N,
    const float* __restrict__ bias,
    ushort_t* __restrict__ Out)        // [MC][N] bf16
{
    __shared__ ushort_t Ahi[128][40];
    __shared__ ushort_t Alo[128][40];
    __shared__ ushort_t Bt[128][40];

    const int tid = threadIdx.x;
    const int m0 = blockIdx.y * 128;
    const int n0 = blockIdx.x * 128;
    const int w = tid >> 6;
    const int l = tid & 63;
    const int wm = w >> 1, wn = w & 1;
    const int kg = l >> 4, lr = l & 15;

    f32x4 acc[4][4] = {};

    for (int k0 = 0; k0 < Ktot; k0 += 32) {
#pragma unroll
        for (int s = 0; s < 4; ++s) {
            int idx = tid + s * 256;
            int arow = idx >> 3;
            int ch = idx & 7;
            int m = m0 + arow;
            const float* src;
            if (k0 < L_) {
                src = Astate + (long)((m >> 5) * 33 + (m & 31)) * L_ + k0 + ch * 4;
            } else {
                src = Aact + (long)m * A_ + (k0 - L_) + ch * 4;
            }
            float4 v = *reinterpret_cast<const float4*>(src);
            unsigned short h0 = bf16_rne(v.x), h1 = bf16_rne(v.y),
                           h2 = bf16_rne(v.z), h3 = bf16_rne(v.w);
            unsigned short e0 = bf16_rne(v.x - bf16_to_f32(h0));
            unsigned short e1 = bf16_rne(v.y - bf16_to_f32(h1));
            unsigned short e2 = bf16_rne(v.z - bf16_to_f32(h2));
            unsigned short e3 = bf16_rne(v.w - bf16_to_f32(h3));
            s16x4 hv = {(short)h0, (short)h1, (short)h2, (short)h3};
            s16x4 lv = {(short)e0, (short)e1, (short)e2, (short)e3};
            *reinterpret_cast<s16x4*>(&Ahi[arow][ch * 4]) = hv;
            *reinterpret_cast<s16x4*>(&Alo[arow][ch * 4]) = lv;
        }
#pragma unroll
        for (int s = 0; s < 2; ++s) {
            int idx = tid + s * 256;
            int brow = idx >> 2;
            int ch = idx & 3;
            s16x8 wv = *reinterpret_cast<const s16x8*>(
                &WT[(long)(n0 + brow) * Ktot + k0 + ch * 8]);
            *reinterpret_cast<s16x8*>(&Bt[brow][ch * 8]) = wv;
        }
        __syncthreads();

        s16x8 ah[4], al[4], bb[4];
#pragma unroll
        for (int i = 0; i < 4; ++i) {
            int r = wm * 64 + i * 16 + lr;
            ah[i] = *reinterpret_cast<const s16x8*>(&Ahi[r][kg * 8]);
            al[i] = *reinterpret_cast<const s16x8*>(&Alo[r][kg * 8]);
        }
#pragma unroll
        for (int j = 0; j < 4; ++j) {
            int r = wn * 64 + j * 16 + lr;
            bb[j] = *reinterpret_cast<const s16x8*>(&Bt[r][kg * 8]);
        }
#pragma unroll
        for (int i = 0; i < 4; ++i)
#pragma unroll
            for (int j = 0; j < 4; ++j) {
                acc[i][j] = __builtin_amdgcn_mfma_f32_16x16x32_bf16(
                    ah[i], bb[j], acc[i][j], 0, 0, 0);
                acc[i][j] = __builtin_amdgcn_mfma_f32_16x16x32_bf16(
                    al[i], bb[j], acc[i][j], 0, 0, 0);
            }
        __syncthreads();
    }

    float bv[4];
#pragma unroll
    for (int j = 0; j < 4; ++j) bv[j] = bias[n0 + wn * 64 + j * 16 + lr];
#pragma unroll
    for (int i = 0; i < 4; ++i)
#pragma unroll
        for (int j = 0; j < 4; ++j)
#pragma unroll
            for (int r = 0; r < 4; ++r) {
                int row = m0 + wm * 64 + i * 16 + kg * 4 + r;
                int col = n0 + wn * 64 + j * 16 + lr;
                float v = fmaxf(acc[i][j][r] + bv[j], 0.f);
                Out[(long)row * N + col] = bf16_rne(v);
            }
}

// Out[m][n] (f32) = A_bf16[m][:] @ WT^T + bias   (K = 1024, no relu)
__global__ __launch_bounds__(256) void mm_bf16(
    const ushort_t* __restrict__ Abf,  // [MC][1024] bf16
    const ushort_t* __restrict__ WT,   // [N][1024] bf16
    int N,
    const float* __restrict__ bias,
    float* __restrict__ Out)           // [MC][N] f32
{
    __shared__ ushort_t At[128][40];
    __shared__ ushort_t Bt[128][40];

    const int tid = threadIdx.x;
    const int m0 = blockIdx.y * 128;
    const int n0 = blockIdx.x * 128;
    const int w = tid >> 6;
    const int l = tid & 63;
    const int wm = w >> 1, wn = w & 1;
    const int kg = l >> 4, lr = l & 15;

    f32x4 acc[4][4] = {};

    for (int k0 = 0; k0 < HID_; k0 += 32) {
#pragma unroll
        for (int s = 0; s < 2; ++s) {
            int idx = tid + s * 256;
            int arow = idx >> 2;
            int ch = idx & 3;
            s16x8 av = *reinterpret_cast<const s16x8*>(
                &Abf[(long)(m0 + arow) * HID_ + k0 + ch * 8]);
            *reinterpret_cast<s16x8*>(&At[arow][ch * 8]) = av;
        }
#pragma unroll
        for (int s = 0; s < 2; ++s) {
            int idx = tid + s * 256;
            int brow = idx >> 2;
            int ch = idx & 3;
            s16x8 wv = *reinterpret_cast<const s16x8*>(
                &WT[(long)(n0 + brow) * HID_ + k0 + ch * 8]);
            *reinterpret_cast<s16x8*>(&Bt[brow][ch * 8]) = wv;
        }
        __syncthreads();

        s16x8 aa[4], bb[4];
#pragma unroll
        for (int i = 0; i < 4; ++i)
            aa[i] = *reinterpret_cast<const s16x8*>(&At[wm * 64 + i * 16 + lr][kg * 8]);
#pragma unroll
        for (int j = 0; j < 4; ++j)
            bb[j] = *reinterpret_cast<const s16x8*>(&Bt[wn * 64 + j * 16 + lr][kg * 8]);
#pragma unroll
        for (int i = 0; i < 4; ++i)
#pragma unroll
            for (int j = 0; j < 4; ++j)
                acc[i][j] = __builtin_amdgcn_mfma_f32_16x16x32_bf16(
                    aa[i], bb[j], acc[i][j], 0, 0, 0);
        __syncthreads();
    }

    float bv[4];
#pragma unroll
    for (int j = 0; j < 4; ++j) bv[j] = bias[n0 + wn * 64 + j * 16 + lr];
#pragma unroll
    for (int i = 0; i < 4; ++i)
#pragma unroll
        for (int j = 0; j < 4; ++j)
#pragma unroll
            for (int r = 0; r < 4; ++r) {
                int row = m0 + wm * 64 + i * 16 + kg * 4 + r;
                int col = n0 + wn * 64 + j * 16 + lr;
                Out[(long)row * N + col] = acc[i][j][r] + bv[j];
            }
}

// harm[m] = sigmoid(hh[m][:] . Wh2 + bh2), one wave per row.
__global__ __launch_bounds__(256) void harm_reduce(
    const ushort_t* __restrict__ hh,  // [MC][1024] bf16
    const float* __restrict__ Wh2,    // [1024]
    const float* __restrict__ bh2,
    float* __restrict__ harm)
{
    const int wave = threadIdx.x >> 6;
    const int lane = threadIdx.x & 63;
    const long r = (long)blockIdx.x * 4 + wave;
    const ushort_t* row = hh + r * HID_;
    float s = 0.f;
#pragma unroll
    for (int q = 0; q < 2; ++q) {
        s16x8 a = *reinterpret_cast<const s16x8*>(&row[lane * 16 + q * 8]);
        float4 w0 = *reinterpret_cast<const float4*>(&Wh2[lane * 16 + q * 8]);
        float4 w1 = *reinterpret_cast<const float4*>(&Wh2[lane * 16 + q * 8 + 4]);
        s = fmaf(bf16_to_f32((unsigned short)a[0]), w0.x, s);
        s = fmaf(bf16_to_f32((unsigned short)a[1]), w0.y, s);
        s = fmaf(bf16_to_f32((unsigned short)a[2]), w0.z, s);
        s = fmaf(bf16_to_f32((unsigned short)a[3]), w0.w, s);
        s = fmaf(bf16_to_f32((unsigned short)a[4]), w1.x, s);
        s = fmaf(bf16_to_f32((unsigned short)a[5]), w1.y, s);
        s = fmaf(bf16_to_f32((unsigned short)a[6]), w1.z, s);
        s = fmaf(bf16_to_f32((unsigned short)a[7]), w1.w, s);
    }
#pragma unroll
    for (int off = 32; off; off >>= 1) s += __shfl_down(s, off);
    if (lane == 0) {
        float x = s + bh2[0];
        harm[r] = 1.f / (1.f + expf(-x));
    }
}

// ---------------------------------------------------------------------------
extern "C" void kernel_launch(void* const* d_in, const int* in_sizes, int n_in,
                              void* d_out, int out_size, void* d_ws, size_t ws_size,
                              hipStream_t stream)
{
    const float* initial = (const float*)d_in[0];
    const float* actions = (const float*)d_in[1];
    const float* Wae = (const float*)d_in[2];
    const float* bae = (const float*)d_in[3];
    const float* Wt1 = (const float*)d_in[4];
    const float* bt1 = (const float*)d_in[5];
    const float* Wt2 = (const float*)d_in[6];
    const float* bt2 = (const float*)d_in[7];
    const float* Wt3 = (const float*)d_in[8];
    const float* bt3 = (const float*)d_in[9];
    const float* Wo1 = (const float*)d_in[10];
    const float* bo1 = (const float*)d_in[11];
    const float* Wo2 = (const float*)d_in[12];
    const float* bo2 = (const float*)d_in[13];
    const float* Wh1 = (const float*)d_in[14];
    const float* bh1 = (const float*)d_in[15];
    const float* Wh2 = (const float*)d_in[16];
    const float* bh2 = (const float*)d_in[17];

    float* out = (float*)d_out;
    float* states = out;                                    // [B][33][512]
    float* obs = out + (size_t)B_ * 33 * L_;                // [B][32][512]
    float* harm = obs + (size_t)B_ * HOR_ * L_;             // [B][32]

    // ws layout
    char* wsb = (char*)d_ws;
    size_t off = 0;
    auto alloc = [&](size_t bytes) { char* q = wsb + off; off += bytes; return q; };
    ushort_t* WT_o1 = (ushort_t*)alloc((size_t)HID_ * L_ * 2);
    ushort_t* WT_o2 = (ushort_t*)alloc((size_t)L_ * HID_ * 2);
    ushort_t* WT_h1 = (ushort_t*)alloc((size_t)HID_ * 576 * 2);
    _Float16* Wt1h = (_Float16*)alloc((size_t)HID_ * 576 * 2);
    _Float16* Wt1l = (_Float16*)alloc((size_t)HID_ * 576 * 2);
    _Float16* Wt2h = (_Float16*)alloc((size_t)HID_ * HID_ * 2);
    _Float16* Wt2l = (_Float16*)alloc((size_t)HID_ * HID_ * 2);
    _Float16* Wt3h = (_Float16*)alloc((size_t)L_ * HID_ * 2);
    _Float16* Wt3l = (_Float16*)alloc((size_t)L_ * HID_ * 2);
    _Float16* sth  = (_Float16*)alloc((size_t)B_ * L_ * 2);
    _Float16* stl  = (_Float16*)alloc((size_t)B_ * L_ * 2);
    _Float16* h1h  = (_Float16*)alloc((size_t)B_ * HID_ * 2);
    _Float16* h1l  = (_Float16*)alloc((size_t)B_ * HID_ * 2);
    _Float16* h2h  = (_Float16*)alloc((size_t)B_ * HID_ * 2);
    _Float16* h2l  = (_Float16*)alloc((size_t)B_ * HID_ * 2);
    float* ae = (float*)alloc(0);  // placed last; size depends on mode
    const size_t need_batched = off + (size_t)B_ * HOR_ * A_ * 4;
    const bool batched_ae = (ws_size >= need_batched);
    // fallback needs only [B][64] f32 at the same offset

    // phase-2 activation buffer overlays h1h..h2l (33.5 MB)
    ushort_t* oh = (ushort_t*)h1h;

    // one-time weight prep
    cast_transpose<<<dim3(2, HID_), 256, 0, stream>>>(Wo1, WT_o1, L_, HID_);
    cast_transpose<<<dim3(4, L_), 256, 0, stream>>>(Wo2, WT_o2, HID_, L_);
    cast_transpose<<<dim3(3, HID_), 256, 0, stream>>>(Wh1, WT_h1, 576, HID_);
    split_transpose<<<dim3(3, HID_), 256, 0, stream>>>(Wt1, Wt1h, Wt1l, 576, HID_);
    split_transpose<<<dim3(4, HID_), 256, 0, stream>>>(Wt2, Wt2h, Wt2l, HID_, HID_);
    split_transpose<<<dim3(4, L_), 256, 0, stream>>>(Wt3, Wt3h, Wt3l, HID_, L_);

    init_split<<<(B_ * L_) / 256, 256, 0, stream>>>(initial, states, sth, stl);
    if (batched_ae)
        ae_all<<<(B_ * HOR_) / 4, 256, 0, stream>>>(actions, Wae, bae, ae);

    const int ldS = 33 * L_;
    const int lda_ae = batched_ae ? (HOR_ * A_) : A_;

    // ---- Phase 1: serial transition rollout (split-fp16 MFMA) ----
    for (int t = 0; t < HOR_; ++t) {
        if (!batched_ae)
            ae_step<<<B_ / 4, 256, 0, stream>>>(actions, Wae, bae, t, ae);
        const int aoff = batched_ae ? t * A_ : 0;
        // h1 = relu([state, ae] @ Wt1^T + bt1) -> fp16 hi/lo
        trans_gemm<128, true, true, true, false, false>
            <<<dim3(HID_ / 64, B_ / 128), 512, 0, stream>>>(
            sth, stl, L_, 576, ae, lda_ae, aoff,
            Wt1h, Wt1l, bt1, nullptr, 0, h1h, h1l, HID_, nullptr, 0);
        // h2 = relu(h1 @ Wt2^T + bt2) -> fp16 hi/lo
        trans_gemm<128, false, true, true, false, false>
            <<<dim3(HID_ / 64, B_ / 128), 512, 0, stream>>>(
            h1h, h1l, HID_, HID_, nullptr, 0, 0,
            Wt2h, Wt2l, bt2, nullptr, 0, h2h, h2l, HID_, nullptr, 0);
        // next_state = state + h2 @ Wt3^T + bt3 -> f32 states AND split sth/stl
        trans_gemm<64, false, true, false, true, true>
            <<<dim3(L_ / 64, B_ / 64), 512, 0, stream>>>(
            h2h, h2l, HID_, HID_, nullptr, 0, 0,
            Wt3h, Wt3l, bt3, states + (size_t)t * L_, ldS,
            sth, stl, L_, states + (size_t)(t + 1) * L_, ldS);
    }

    // ---- Phase 2: batched obs + harm in bf16 MFMA, 8 chunks of 512 batch ----
    for (int c = 0; c < B_ / CB; ++c) {
        const float* Sc = states + (size_t)c * CB * 33 * L_;
        const float* Ac = actions + (size_t)c * CB * HOR_ * A_;
        mm_split<<<dim3(HID_ / 128, MC / 128), 256, 0, stream>>>(
            Sc, nullptr, L_, WT_o1, HID_, bo1, oh);
        mm_bf16<<<dim3(L_ / 128, MC / 128), 256, 0, stream>>>(
            oh, WT_o2, L_, bo2, obs + (size_t)c * CB * HOR_ * L_);
        mm_split<<<dim3(HID_ / 128, MC / 128), 256, 0, stream>>>(
            Sc, Ac, 576, WT_h1, HID_, bh1, oh);
        harm_reduce<<<MC / 4, 256, 0, stream>>>(
            oh, Wh2, bh2, harm + (size_t)c * CB * HOR_);
    }
}